// Round 10
// baseline (2192.050 us; speedup 1.0000x reference)
//
#include <hip/hip_runtime.h>
#include <math.h>

// PerceiverResampler on MI355X.
// xhat = rownorm(x + frame_emb + media_emb) once (bf16); per-layer LN affine folded
// into Wkv; ALL per-layer weights transpose-cast once upfront (6-layer buffers).
// kv-GEMM: PERSISTENT 8-phase 256x256 pipeline — 256 blocks (1/CU), each owns one
// 256-row A-panel and streams 4 outputs x 16 K-tiles = 64 virtual tiles through one
// continuous pipeline (r7-proven phase/barrier/gate schedule, unchanged).
// r9 BUG FIX: vt = out*16 + ktile (16 K-tiles per output, not 8).

#define DIM   1024
#define DEPTH 6
#define HEADS 8
#define NLAT  64
#define INNER 512
#define FFD   4096
#define XROWS 65536
#define LROWS 1024
#define NBT   16
#define QKVN  1536

typedef __attribute__((ext_vector_type(8))) short bf16x8;
typedef __attribute__((ext_vector_type(4))) float f32x4;

#define WAITV(n) asm volatile("s_waitcnt vmcnt(" #n ")" ::: "memory")

__device__ __forceinline__ short f2bf(float f) {
  union { float f; unsigned u; } v; v.f = f;
  unsigned r = v.u + 0x7fffu + ((v.u >> 16) & 1u);
  return (short)(r >> 16);
}

__device__ __forceinline__ void gload16(const void* g, void* l) {
  __builtin_amdgcn_global_load_lds(
      (const __attribute__((address_space(1))) unsigned int*)g,
      (__attribute__((address_space(3))) unsigned int*)l, 16, 0, 0);
}

__device__ __forceinline__ f32x4 zero_f4() { f32x4 z; z[0]=0.f; z[1]=0.f; z[2]=0.f; z[3]=0.f; return z; }
__device__ __forceinline__ bf16x8 zero_b8() { bf16x8 z;
#pragma unroll
  for (int e=0;e<8;e++) z[e]=0; return z; }

// ---------------- preprocess ----------------
__global__ __launch_bounds__(256)
void prep_kernel(const float* __restrict__ x, const float* __restrict__ fe,
                 const float* __restrict__ me, short* __restrict__ xhat)
{
  int lane = threadIdx.x & 63;
  int r = blockIdx.x*4 + (threadIdx.x >> 6);
  int f = (r >> 8) & 15, tt = (r >> 12) & 7;
  const float4* xp = (const float4*)(x + (size_t)r*DIM);
  const float4* fp = (const float4*)(fe + (size_t)f*DIM);
  const float4* mp = (const float4*)(me + (size_t)tt*DIM);
  float y[16];
  float s = 0.f, sq = 0.f;
#pragma unroll
  for (int k = 0; k < 4; k++) {
    float4 xv = xp[k*64 + lane], fv = fp[k*64 + lane], mv = mp[k*64 + lane];
    float a0 = xv.x+fv.x+mv.x, a1 = xv.y+fv.y+mv.y, a2 = xv.z+fv.z+mv.z, a3 = xv.w+fv.w+mv.w;
    y[k*4+0]=a0; y[k*4+1]=a1; y[k*4+2]=a2; y[k*4+3]=a3;
    s += a0+a1+a2+a3; sq += a0*a0+a1*a1+a2*a2+a3*a3;
  }
#pragma unroll
  for (int off = 32; off >= 1; off >>= 1) {
    s  += __shfl_xor(s,  off, 64);
    sq += __shfl_xor(sq, off, 64);
  }
  float mean = s * (1.0f/DIM);
  float var  = sq * (1.0f/DIM) - mean*mean;
  float rs = rsqrtf(var + 1e-5f);
  short4* op = (short4*)(xhat + (size_t)r*DIM);
#pragma unroll
  for (int k = 0; k < 4; k++) {
    short4 o;
    o.x = f2bf((y[k*4+0]-mean)*rs); o.y = f2bf((y[k*4+1]-mean)*rs);
    o.z = f2bf((y[k*4+2]-mean)*rs); o.w = f2bf((y[k*4+3]-mean)*rs);
    op[k*64 + lane] = o;
  }
}

// ---------------- block-wide 2-value reduce ----------------
__device__ __forceinline__ void reduce2(float& s, float& sq, float* sh) {
#pragma unroll
  for (int off = 32; off >= 1; off >>= 1) {
    s  += __shfl_xor(s,  off, 64);
    sq += __shfl_xor(sq, off, 64);
  }
  int t = threadIdx.x;
  if ((t & 63) == 0) { sh[(t >> 6)*2] = s; sh[(t >> 6)*2 + 1] = sq; }
  __syncthreads();
  s  = sh[0] + sh[2] + sh[4] + sh[6];
  sq = sh[1] + sh[3] + sh[5] + sh[7];
}

// ---------------- LN (hbuf producer) ----------------
template<bool OBF>
__global__ __launch_bounds__(256)
void ln_kernel(const float* __restrict__ in, const float* __restrict__ w,
               const float* __restrict__ b, void* __restrict__ outp)
{
  __shared__ float sh[8];
  int r = blockIdx.x, t = threadIdx.x;
  float4 xv = ((const float4*)(in + (size_t)r*DIM))[t];
  float s = xv.x+xv.y+xv.z+xv.w;
  float sq = xv.x*xv.x+xv.y*xv.y+xv.z*xv.z+xv.w*xv.w;
  reduce2(s, sq, sh);
  float mean = s*(1.0f/DIM), var = sq*(1.0f/DIM) - mean*mean;
  float rs = rsqrtf(var + 1e-5f);
  float4 wv = ((const float4*)w)[t], bv = ((const float4*)b)[t];
  float o0 = (xv.x-mean)*rs*wv.x + bv.x;
  float o1 = (xv.y-mean)*rs*wv.y + bv.y;
  float o2 = (xv.z-mean)*rs*wv.z + bv.z;
  float o3 = (xv.w-mean)*rs*wv.w + bv.w;
  if (OBF) {
    short4 o; o.x=f2bf(o0); o.y=f2bf(o1); o.z=f2bf(o2); o.w=f2bf(o3);
    ((short4*)((short*)outp + (size_t)r*DIM))[t] = o;
  } else {
    float4 o; o.x=o0; o.y=o1; o.z=o2; o.w=o3;
    ((float4*)((float*)outp + (size_t)r*DIM))[t] = o;
  }
}

// ---------------- lat init + LN(layer0 lnl); one row per block ----------------
__global__ __launch_bounds__(256)
void latinit_ln_kernel(const float* __restrict__ latents, const float* __restrict__ w,
                       const float* __restrict__ b, float* __restrict__ lat,
                       short* __restrict__ lnlat)
{
  __shared__ float sh[8];
  int r = blockIdx.x, t = threadIdx.x;
  int i = r & 63;
  float4 a = ((const float4*)(latents + (size_t)i*DIM))[t];
  ((float4*)(lat + (size_t)r*DIM))[t] = a;
  float s = a.x+a.y+a.z+a.w;
  float sq = a.x*a.x+a.y*a.y+a.z*a.z+a.w*a.w;
  reduce2(s, sq, sh);
  float mean = s*(1.0f/DIM), var = sq*(1.0f/DIM) - mean*mean;
  float rs = rsqrtf(var + 1e-5f);
  float4 wv = ((const float4*)w)[t], bv = ((const float4*)b)[t];
  short4 o;
  o.x = f2bf((a.x-mean)*rs*wv.x + bv.x);
  o.y = f2bf((a.y-mean)*rs*wv.y + bv.y);
  o.z = f2bf((a.z-mean)*rs*wv.z + bv.z);
  o.w = f2bf((a.w-mean)*rs*wv.w + bv.w);
  ((short4*)(lnlat + (size_t)r*DIM))[t] = o;
}

// ---------------- kvb: split-K partials + reduce ----------------
__global__ __launch_bounds__(256)
void kvbp_kernel(const float* __restrict__ lnm_b, const float* __restrict__ Wkv,
                 float* __restrict__ kvb_part)
{
  int z = blockIdx.x, i = blockIdx.y, t = threadIdx.x;
  const float* W = Wkv + (size_t)i*DIM*DIM;
  const float* bv = lnm_b + (size_t)i*DIM;
  float acc0=0,acc1=0,acc2=0,acc3=0;
  for (int k = z*64; k < z*64+64; k++) {
    float b = bv[k];
    const float* Wr = W + (size_t)k*DIM;
    acc0 += b * Wr[t];       acc1 += b * Wr[t+256];
    acc2 += b * Wr[t+512];   acc3 += b * Wr[t+768];
  }
  float* o = kvb_part + (size_t)(i*16 + z)*DIM;
  o[t] = acc0; o[t+256] = acc1; o[t+512] = acc2; o[t+768] = acc3;
}

__global__ __launch_bounds__(256)
void kvbred_kernel(const float* __restrict__ kvb_part, float* __restrict__ kvb)
{
  int i = blockIdx.x, t = threadIdx.x;
#pragma unroll
  for (int j = 0; j < 4; j++) {
    int col = t + j*256;
    float s = 0.f;
#pragma unroll
    for (int z = 0; z < 16; z++) s += kvb_part[(size_t)(i*16 + z)*DIM + col];
    kvb[i*DIM + col] = s;
  }
}

// ---------------- all-layer transpose-cast (once upfront) ----------------
__global__ __launch_bounds__(256)
void tcast_all6_kernel(const float* __restrict__ Wkv, const float* __restrict__ Wq,
                       const float* __restrict__ Wo, const float* __restrict__ W1,
                       const float* __restrict__ W2, const float* __restrict__ lnm_w,
                       short* __restrict__ Wkvf_a, short* __restrict__ qkvW_a,
                       short* __restrict__ Wo_a, short* __restrict__ W1_a,
                       short* __restrict__ W2_a)
{
  int L = blockIdx.x / 2816;
  int b = blockIdx.x % 2816;
  const float* lWkv = Wkv + (size_t)L*DIM*DIM;
  const float* src; short* dst; const float* fold = nullptr; float scale = 1.0f;
  int K, N, bx, ntx;
  if (b < 256)      { src=lWkv; dst=Wkvf_a + (size_t)L*DIM*DIM; fold=lnm_w + (size_t)L*DIM; K=1024; N=1024; bx=b; ntx=16; }
  else if (b < 384) { src=Wq + (size_t)L*DIM*INNER; dst=qkvW_a + (size_t)L*QKVN*DIM; scale=0.125f; K=1024; N=512; bx=b-256; ntx=8; }
  else if (b < 640) { src=lWkv; dst=qkvW_a + (size_t)L*QKVN*DIM + (size_t)512*1024; K=1024; N=1024; bx=b-384; ntx=16; }
  else if (b < 768) { src=Wo + (size_t)L*INNER*DIM; dst=Wo_a + (size_t)L*INNER*DIM; K=512;  N=1024; bx=b-640; ntx=16; }
  else if (b < 1792){ src=W1 + (size_t)L*DIM*FFD; dst=W1_a + (size_t)L*DIM*FFD; K=1024; N=4096; bx=b-768; ntx=64; }
  else              { src=W2 + (size_t)L*FFD*DIM; dst=W2_a + (size_t)L*FFD*DIM; K=4096; N=1024; bx=b-1792; ntx=16; }
  int n0 = (bx % ntx)*64, k0 = (bx / ntx)*64;
  __shared__ float tile[64][65];
  int t = threadIdx.x;
#pragma unroll
  for (int i = 0; i < 16; i++) {
    int rr = (t >> 6) + i*4, cc = t & 63;
    float v = src[(size_t)(k0+rr)*N + n0 + cc] * scale;
    if (fold) v *= fold[k0 + rr];
    tile[rr][cc] = v;
  }
  __syncthreads();
#pragma unroll
  for (int i = 0; i < 16; i++) {
    int nn = (t >> 6) + i*4, kk = t & 63;
    dst[(size_t)(n0+nn)*K + k0 + kk] = f2bf(tile[kk][nn]);
  }
}

// ---------------- persistent 256x256 8-phase GEMM (kv projection) ----------------
// 256 blocks (1/CU). Block owns one 256-row A-panel; virtual tile vt = out*16 + ktile
// (4 outputs x 16 K-tiles = 64). Buffer parity vt&1; schedule = r7 proven.
__global__ __launch_bounds__(512, 1)
void gemm256pp_kernel(const short* __restrict__ A, const short* __restrict__ Bt,
                      short* __restrict__ C, const float* __restrict__ bias)
{
  __shared__ __align__(16) short lds[65536];   // 128 KiB
  char* ldsc = (char*)lds;
  const int t = threadIdx.x, lane = t & 63, wid = t >> 6;
  const int wm = wid >> 2, wn = wid & 3;
  const int K = DIM, N = DIM;

  const int b = blockIdx.x;                    // 256
  const int bm = (b & 7)*32 + (b >> 3);        // 32 consecutive panels per XCD
  const int m0 = bm * 256;

  f32x4 acc[8][4];
#pragma unroll
  for (int m=0;m<8;m++)
#pragma unroll
    for (int n=0;n<4;n++) acc[m][n] = zero_f4();

  // hoisted staging addresses
  const int hK = K << 7;                       // 128*K elems
  const short* pA[2]; const short* pB0[2]; int ldst[2];
#pragma unroll
  for (int i = 0; i < 2; i++) {
    int chunk = i*512 + t;
    int rh = chunk >> 3, sl = chunk & 7;
    int ss = sl ^ (rh & 7);
    pA[i]  = A + (size_t)(m0 + rh)*K + ss*8;
    pB0[i] = Bt + (size_t)rh*K + ss*8;
    ldst[i] = (i*512 + (wid << 6))*16;
  }
  // stage virtual tile vt (ktile=vt&15, out=vt>>4), matrix mat, half
  auto stage = [&](int vt, int mat, int half) {
    char* dbase = ldsc + mat*65536 + (vt & 1)*32768 + half*16384;
    const int koff = (vt & 15)*64;
    const size_t bout = (size_t)(vt >> 4)*256*K;
#pragma unroll
    for (int i = 0; i < 2; i++) {
      const short* src = mat ? (pB0[i] + bout + half*hK + koff)
                             : (pA[i] + half*hK + koff);
      gload16(src, dbase + ldst[i]);
    }
  };

  // hoisted fragment bases (row&7 == lane&7)
  const int sk0 = (((lane >> 4)    ) ^ (lane & 7)) * 16;
  const int sk1 = ((4 + (lane >> 4)) ^ (lane & 7)) * 16;
  const int rowb = (lane & 15) * 128;
  const char* aB[2] = { ldsc + wm*16384 + rowb + sk0, ldsc + wm*16384 + rowb + sk1 };
  const char* bB[2] = { ldsc + 65536 + wn*8192 + rowb + sk0, ldsc + 65536 + wn*8192 + rowb + sk1 };

#define PHASE(BUF, Q, STAGE_STMT, GATE) do {                               \
    if ((Q) == 0) {                                                        \
      _Pragma("unroll") for (int n_=0;n_<4;n_++)                           \
        _Pragma("unroll") for (int k_=0;k_<2;k_++)                         \
          bfr[n_][k_] = *(const bf16x8*)(bB[k_] + (BUF)*32768 + n_*2048);  \
    }                                                                      \
    _Pragma("unroll") for (int i_=0;i_<2;i_++)                             \
      _Pragma("unroll") for (int k_=0;k_<2;k_++)                           \
        afr[i_][k_] = *(const bf16x8*)(aB[k_] + (BUF)*32768 + (2*(Q)+i_)*2048); \
    STAGE_STMT;                                                            \
    GATE;                                                                  \
    __builtin_amdgcn_sched_barrier(0);                                     \
    __builtin_amdgcn_s_barrier();                                          \
    asm volatile("s_waitcnt lgkmcnt(0)" ::: "memory");                     \
    __builtin_amdgcn_sched_barrier(0);                                     \
    __builtin_amdgcn_s_setprio(1);                                         \
    _Pragma("unroll") for (int k_=0;k_<2;k_++)                             \
      _Pragma("unroll") for (int i_=0;i_<2;i_++)                           \
        _Pragma("unroll") for (int n_=0;n_<4;n_++)                         \
          acc[2*(Q)+i_][n_] = __builtin_amdgcn_mfma_f32_16x16x32_bf16(     \
              afr[i_][k_], bfr[n_][k_], acc[2*(Q)+i_][n_], 0, 0, 0);       \
    __builtin_amdgcn_s_setprio(0);                                         \
    __builtin_amdgcn_sched_barrier(0);                                     \
    __builtin_amdgcn_s_barrier();                                          \
  } while (0)

  const int NVT = 64;   // 4 outputs x 16 K-tiles
  // prologue: A(0), B(0), B(1)
  stage(0, 0, 0); stage(0, 0, 1); stage(0, 1, 0); stage(0, 1, 1);
  stage(1, 1, 0); stage(1, 1, 1);
  WAITV(4);
  __builtin_amdgcn_sched_barrier(0);
  __builtin_amdgcn_s_barrier();

  const int g = lane >> 4;
#pragma unroll 1
  for (int u = 0; u < 32; ++u) {
    const int vt0 = 2*u, vt1 = vt0 + 1;
    const bool more = (vt0 + 2 < NVT);
    bf16x8 bfr[4][2], afr[2][2];
    PHASE(0, 0, stage(vt1, 0, 0),               (void)0);
    PHASE(0, 1, stage(vt1, 0, 1),               (void)0);
    PHASE(0, 2, if (more) stage(vt0+2, 1, 0),   (void)0);
    PHASE(0, 3, if (more) stage(vt0+2, 1, 1),   if (more) { WAITV(4); } else { WAITV(0); });
    PHASE(1, 0, if (more) stage(vt0+2, 0, 0),   (void)0);
    PHASE(1, 1, if (more) stage(vt0+2, 0, 1),   (void)0);
    PHASE(1, 2, if (more) stage(vt1+2, 1, 0),   (void)0);
    PHASE(1, 3, if (more) stage(vt1+2, 1, 1),   if (more) { WAITV(4); });
    if ((u & 7) == 7) {
      // output (m0, n0) complete: write + rezero
      const int n0 = (u >> 3) * 256;
#pragma unroll
      for (int m=0;m<8;m++) {
#pragma unroll
        for (int n=0;n<4;n++) {
#pragma unroll
          for (int r=0;r<4;r++) {
            int mm = m0 + wm*128 + m*16 + g*4 + r;
            int nn = n0 + wn*64 + n*16 + (lane & 15);
            C[(size_t)mm*N + nn] = f2bf(acc[m][n][r] + bias[nn]);
          }
          acc[m][n] = zero_f4();
        }
      }
    }
  }
#undef PHASE
}

// ---------------- 128x128 GEMM (small shapes) ----------------
// EPI: 0 bf16 store, 1 gelu+bf16, 2 f32 +=, 4 f32 partial store (split-K z)
template<int EPI, bool HAS_BIAS>
__global__ __launch_bounds__(256, 2)
void gemm_kernel(const short* __restrict__ A, const short* __restrict__ Bt,
                 void* __restrict__ Cout, const float* __restrict__ bias,
                 int M, int N, int K, int ldk)
{
  __shared__ __align__(16) short As[128*64];
  __shared__ __align__(16) short Bs[128*64];
  const int t = threadIdx.x;
  const int lane = t & 63, w = t >> 6;
  const int m0 = blockIdx.x * 128, n0 = blockIdx.y * 128;
  const int wr = (w >> 1) * 64, wc = (w & 1) * 64;
  const short* Ap = A + (size_t)blockIdx.z * K;
  const short* Btp = Bt + (size_t)blockIdx.z * K;

  f32x4 acc[4][4];
#pragma unroll
  for (int i=0;i<4;i++)
#pragma unroll
    for (int j=0;j<4;j++) acc[i][j] = zero_f4();

  for (int kt = 0; kt < K; kt += 64) {
#pragma unroll
    for (int i = 0; i < 4; i++) {
      int chunk = i*256 + t;
      int row = chunk >> 3, slot = chunk & 7;
      int ss = slot ^ (row & 7);
      gload16(Ap + (size_t)(m0 + row)*ldk + kt + ss*8,
              (char*)As + (i*256 + (w<<6))*16);
    }
#pragma unroll
    for (int i = 0; i < 4; i++) {
      int chunk = i*256 + t;
      int row = chunk >> 3, slot = chunk & 7;
      int ss = slot ^ (row & 7);
      gload16(Btp + (size_t)(n0 + row)*ldk + kt + ss*8,
              (char*)Bs + (i*256 + (w<<6))*16);
    }
    __syncthreads();

#pragma unroll
    for (int ks = 0; ks < 2; ks++) {
      bf16x8 af[4], bfr[4];
#pragma unroll
      for (int i=0;i<4;i++) {
        int row = wr + i*16 + (lane & 15);
        int slot = (ks*4 + (lane >> 4)) ^ (row & 7);
        af[i] = *(const bf16x8*)((const char*)As + row*128 + slot*16);
        int nrow = wc + i*16 + (lane & 15);
        int nslot = (ks*4 + (lane >> 4)) ^ (nrow & 7);
        bfr[i] = *(const bf16x8*)((const char*)Bs + nrow*128 + nslot*16);
      }
#pragma unroll
      for (int i=0;i<4;i++)
#pragma unroll
        for (int j=0;j<4;j++)
          acc[i][j] = __builtin_amdgcn_mfma_f32_16x16x32_bf16(af[i], bfr[j], acc[i][j], 0, 0, 0);
    }
    __syncthreads();
  }

  const int g = lane >> 4;
#pragma unroll
  for (int i=0;i<4;i++) {
#pragma unroll
    for (int j=0;j<4;j++) {
#pragma unroll
      for (int r=0;r<4;r++) {
        int m = m0 + wr + i*16 + g*4 + r;
        int n = n0 + wc + j*16 + (lane & 15);
        float v = acc[i][j][r];
        if (EPI == 0) {
          if (HAS_BIAS) v += bias[n];
          ((short*)Cout)[(size_t)m*N + n] = f2bf(v);
        } else if (EPI == 1) {
          if (HAS_BIAS) v += bias[n];
          float gl = 0.5f * v * (1.0f + erff(v * 0.70710678f));
          ((short*)Cout)[(size_t)m*N + n] = f2bf(gl);
        } else if (EPI == 2) {
          if (HAS_BIAS) v += bias[n];
          float* o = (float*)Cout + (size_t)m*N + n;
          *o += v;
        } else {
          ((float*)Cout)[(size_t)blockIdx.z*M*N + (size_t)m*N + n] = v;
        }
      }
    }
  }
}

// ---------------- W2 split-K reduce + residual + LN(next lnl or final fln) ----------------
template<bool LAST>
__global__ __launch_bounds__(256)
void w2red_ln_kernel(const float* __restrict__ part, const float* __restrict__ b2,
                     float* __restrict__ lat, const float* __restrict__ w,
                     const float* __restrict__ bb, void* __restrict__ dst)
{
  __shared__ float sh[8];
  int r = blockIdx.x, t = threadIdx.x;
  int idx = r*256 + t;
  float4 a = ((float4*)lat)[idx];
  float4 b4 = ((const float4*)b2)[t];
  a.x += b4.x; a.y += b4.y; a.z += b4.z; a.w += b4.w;
#pragma unroll
  for (int z = 0; z < 4; z++) {
    float4 p = ((const float4*)(part + (size_t)z*LROWS*DIM))[idx];
    a.x += p.x; a.y += p.y; a.z += p.z; a.w += p.w;
  }
  ((float4*)lat)[idx] = a;
  float s = a.x+a.y+a.z+a.w;
  float sq = a.x*a.x+a.y*a.y+a.z*a.z+a.w*a.w;
  reduce2(s, sq, sh);
  float mean = s*(1.0f/DIM), var = sq*(1.0f/DIM) - mean*mean;
  float rs = rsqrtf(var + 1e-5f);
  float4 wv = ((const float4*)w)[t], bv = ((const float4*)bb)[t];
  float o0 = (a.x-mean)*rs*wv.x + bv.x;
  float o1 = (a.y-mean)*rs*wv.y + bv.y;
  float o2 = (a.z-mean)*rs*wv.z + bv.z;
  float o3 = (a.w-mean)*rs*wv.w + bv.w;
  if (LAST) {
    float4 o; o.x=o0; o.y=o1; o.z=o2; o.w=o3;
    ((float4*)((float*)dst + (size_t)r*DIM))[t] = o;
  } else {
    short4 o; o.x=f2bf(o0); o.y=f2bf(o1); o.z=f2bf(o2); o.w=f2bf(o3);
    ((short4*)((short*)dst + (size_t)r*DIM))[t] = o;
  }
}

// ---------------- attention pass 1: split-K flash, register softmax ----------------
__global__ __launch_bounds__(256, 2)
void attn_part_kernel(const short* __restrict__ qkvlat, const short* __restrict__ kvbuf,
                      float* __restrict__ part_O, float* __restrict__ part_m,
                      float* __restrict__ part_l)
{
  __shared__ __align__(16) short q_sh[64*64];
  __shared__ __align__(16) short K_sh[128*64];
  __shared__ __align__(16) short VT_sh[64*128];
  __shared__ __align__(16) short P_sh[64*132];

  const int t = threadIdx.x, lane = t & 63, w = t >> 6;
  const int bid = blockIdx.x;
  const int s = bid & 7, bh = bid >> 3;
  const int h = bh & 7, bt = bh >> 3;

  {
    const short* qsrc = qkvlat + (size_t)(bt*64)*QKVN + h*64;
#pragma unroll
    for (int i = 0; i < 2; i++) {
      int chunk = i*256 + t;
      int row = chunk >> 3, slot = chunk & 7;
      gload16(qsrc + (size_t)row*QKVN + ((slot ^ (row & 7))*8),
              (char*)q_sh + (i*256 + (w<<6))*16);
    }
  }

  float m_run[4], l_run[4];
#pragma unroll
  for (int r=0;r<4;r++){ m_run[r] = -1e30f; l_run[r] = 0.f; }
  f32x4 oacc[4];
#pragma unroll
  for (int j=0;j<4;j++) oacc[j] = zero_f4();

  const int nch = (s == 7) ? 5 : 4;
  for (int c5 = 0; c5 < nch; c5++) {
    __syncthreads();
    const bool isLat = (c5 == 4);
    const int jv = isLat ? 4 : 8;
    const short* kbase; int kstride, valid;
    if (!isLat) {
      kbase = kvbuf + ((size_t)bt*4096 + (s*4 + c5)*128)*DIM + h*64;
      kstride = DIM; valid = 128;
    } else {
      kbase = qkvlat + (size_t)(bt*64)*QKVN + 512 + h*64;
      kstride = QKVN; valid = 64;
    }
    const short* vbase = kbase + 512;

#pragma unroll
    for (int i = 0; i < 4; i++) {
      int chunk = i*256 + t;
      int row = chunk >> 3, slot = chunk & 7;
      gload16(kbase + (size_t)row*kstride + ((slot ^ (row & 7))*8),
              (char*)K_sh + (i*256 + (w<<6))*16);
    }
#pragma unroll
    for (int i = 0; i < 4; i++) {
      int c = i*256 + t;
      int row = c >> 3, slot = c & 7;
      bf16x8 v = (row < valid) ? *(const bf16x8*)(vbase + (size_t)row*kstride + slot*8) : zero_b8();
      int kslot = row >> 3;
#pragma unroll
      for (int e=0;e<8;e++) {
        int dh = slot*8 + e;
        VT_sh[dh*128 + ((kslot ^ (dh & 7))*8) + (row & 7)] = v[e];
      }
    }
    __syncthreads();

    f32x4 sacc[8];
#pragma unroll
    for (int j=0;j<8;j++) sacc[j] = zero_f4();
#pragma unroll
    for (int ks=0; ks<2; ks++) {
      int arow = w*16 + (lane & 15);
      int aslot = (ks*4 + (lane >> 4)) ^ (arow & 7);
      bf16x8 af = *(const bf16x8*)((const char*)q_sh + arow*128 + aslot*16);
#pragma unroll
      for (int j=0;j<8;j++) {
        int brow = j*16 + (lane & 15);
        int bslot = (ks*4 + (lane >> 4)) ^ (brow & 7);
        bf16x8 bv = *(const bf16x8*)((const char*)K_sh + brow*128 + bslot*16);
        sacc[j] = __builtin_amdgcn_mfma_f32_16x16x32_bf16(af, bv, sacc[j], 0, 0, 0);
      }
    }

    float mx[4];
#pragma unroll
    for (int r=0;r<4;r++) mx[r] = -1e30f;
#pragma unroll
    for (int j=0;j<8;j++) {
      if (j < jv) {
#pragma unroll
        for (int r=0;r<4;r++) mx[r] = fmaxf(mx[r], sacc[j][r]);
      }
    }
#pragma unroll
    for (int m2=1; m2<16; m2<<=1) {
#pragma unroll
      for (int r=0;r<4;r++) mx[r] = fmaxf(mx[r], __shfl_xor(mx[r], m2, 64));
    }
    float alpha[4], rowsum[4];
#pragma unroll
    for (int r=0;r<4;r++) {
      float nm = fmaxf(m_run[r], mx[r]);
      alpha[r] = __expf(m_run[r] - nm);
      m_run[r] = nm;
      rowsum[r] = 0.f;
    }
#pragma unroll
    for (int j=0;j<8;j++) {
#pragma unroll
      for (int r=0;r<4;r++) {
        float p = 0.f;
        if (j < jv) { p = __expf(sacc[j][r] - m_run[r]); rowsum[r] += p; }
        P_sh[(w*16 + (lane>>4)*4 + r)*132 + j*16 + (lane & 15)] = f2bf(p);
      }
    }
#pragma unroll
    for (int m2=1; m2<16; m2<<=1) {
#pragma unroll
      for (int r=0;r<4;r++) rowsum[r] += __shfl_xor(rowsum[r], m2, 64);
    }
#pragma unroll
    for (int r=0;r<4;r++) l_run[r] = l_run[r]*alpha[r] + rowsum[r];
#pragma unroll
    for (int j=0;j<4;j++) {
#pragma unroll
      for (int r=0;r<4;r++) oacc[j][r] *= alpha[r];
    }
    __syncthreads();

#pragma unroll
    for (int ks=0; ks<4; ks++) {
      int prow = w*16 + (lane & 15);
      bf16x8 af = *(const bf16x8*)((const char*)P_sh + prow*264 + ks*64 + (lane >> 4)*16);
#pragma unroll
      for (int j=0;j<4;j++) {
        int dh = j*16 + (lane & 15);
        int kslot = (ks*4 + (lane >> 4)) ^ (dh & 7);
        bf16x8 bv = *(const bf16x8*)((const char*)VT_sh + dh*256 + kslot*16);
        oacc[j] = __builtin_amdgcn_mfma_f32_16x16x32_bf16(af, bv, oacc[j], 0, 0, 0);
      }
    }
  }

  {
    float* Ob = part_O + (size_t)bid*4096;
    int rbase = w*16 + (lane>>4)*4;
#pragma unroll
    for (int j=0;j<4;j++) {
#pragma unroll
      for (int r=0;r<4;r++)
        Ob[(rbase + r)*64 + j*16 + (lane & 15)] = oacc[j][r];
    }
    if ((lane & 15) == 0) {
#pragma unroll
      for (int r=0;r<4;r++) {
        part_m[(size_t)bid*64 + rbase + r] = m_run[r];
        part_l[(size_t)bid*64 + rbase + r] = l_run[r];
      }
    }
  }
}

// ---------------- attention pass 2 ----------------
__global__ __launch_bounds__(256)
void attn_combine_kernel(const float* __restrict__ part_O, const float* __restrict__ part_m,
                         const float* __restrict__ part_l, short* __restrict__ obuf)
{
  int bh = blockIdx.x, t = threadIdx.x;
  int q = t >> 2, c0 = (t & 3) * 16;
  int bt = bh >> 3, h = bh & 7;
  float m8[8], w8[8];
  float mmax = -1e30f;
#pragma unroll
  for (int s=0;s<8;s++) { m8[s] = part_m[(size_t)(bh*8+s)*64 + q]; mmax = fmaxf(mmax, m8[s]); }
  float lt = 0.f;
#pragma unroll
  for (int s=0;s<8;s++) { w8[s] = __expf(m8[s] - mmax); lt += w8[s] * part_l[(size_t)(bh*8+s)*64 + q]; }
  float inv = 1.0f / lt;
  float4 acc[4];
#pragma unroll
  for (int u=0;u<4;u++) { acc[u].x=0.f; acc[u].y=0.f; acc[u].z=0.f; acc[u].w=0.f; }
#pragma unroll
  for (int s=0;s<8;s++) {
    const float4* Ob = (const float4*)(part_O + ((size_t)(bh*8+s)*64 + q)*64 + c0);
#pragma unroll
    for (int u=0;u<4;u++) {
      float4 v = Ob[u];
      acc[u].x += w8[s]*v.x; acc[u].y += w8[s]*v.y;
      acc[u].z += w8[s]*v.z; acc[u].w += w8[s]*v.w;
    }
  }
  short* ob = obuf + (size_t)(bt*64 + q)*INNER + h*64 + c0;
#pragma unroll
  for (int u=0;u<4;u++) {
    short4 o;
    o.x = f2bf(acc[u].x*inv); o.y = f2bf(acc[u].y*inv);
    o.z = f2bf(acc[u].z*inv); o.w = f2bf(acc[u].w*inv);
    ((short4*)ob)[u] = o;
  }
}

// ---------------- launch ----------------
extern "C" void kernel_launch(void* const* d_in, const int* in_sizes, int n_in,
                              void* d_out, int out_size, void* d_ws, size_t ws_size,
                              hipStream_t stream)
{
  (void)in_sizes; (void)n_in; (void)out_size; (void)ws_size;
  const float* x        = (const float*)d_in[0];
  const float* latents  = (const float*)d_in[1];
  const float* frame_e  = (const float*)d_in[2];
  const float* media_e  = (const float*)d_in[3];
  const float* lnm_w    = (const float*)d_in[4];
  const float* lnm_b    = (const float*)d_in[5];
  const float* lnl_w    = (const float*)d_in[6];
  const float* lnl_b    = (const float*)d_in[7];
  const float* Wq       = (const float*)d_in[8];
  const float* Wkv      = (const float*)d_in[9];
  const float* Wo       = (const float*)d_in[10];
  const float* ffln_w   = (const float*)d_in[11];
  const float* ffln_b   = (const float*)d_in[12];
  const float* W1       = (const float*)d_in[13];
  const float* b1       = (const float*)d_in[14];
  const float* W2       = (const float*)d_in[15];
  const float* b2       = (const float*)d_in[16];
  const float* fln_w    = (const float*)d_in[17];
  const float* fln_b    = (const float*)d_in[18];
  float* out = (float*)d_out;

  char* ws = (char*)d_ws;
  size_t off = 0;
  short* xhat   = (short*)(ws + off); off += (size_t)XROWS*DIM*2;
  short* kvbuf  = (short*)(ws + off); off += (size_t)XROWS*DIM*2;
  short* Wkvf_a = (short*)(ws + off); off += (size_t)DEPTH*DIM*DIM*2;
  short* qkvW_a = (short*)(ws + off); off += (size_t)DEPTH*QKVN*DIM*2;
  short* Wo_a   = (short*)(ws + off); off += (size_t)DEPTH*INNER*DIM*2;
  short* W1_a   = (short*)(ws + off); off += (size_t)DEPTH*DIM*FFD*2;
  short* W2_a   = (short*)(ws + off); off += (size_t)DEPTH*FFD*DIM*2;
  float* kvb    = (float*)(ws + off); off += (size_t)DEPTH*DIM*4;
  float* kvbp   = (float*)(ws + off); off += (size_t)DEPTH*16*DIM*4;
  float* lat    = (float*)(ws + off); off += (size_t)LROWS*DIM*4;
  short* lnlat  = (short*)(ws + off); off += (size_t)LROWS*DIM*2;
  short* qkvlat = (short*)(ws + off); off += (size_t)LROWS*QKVN*2;
  short* obuf   = (short*)(ws + off); off += (size_t)LROWS*INNER*2;
  short* hbuf   = (short*)(ws + off); off += (size_t)LROWS*DIM*2;
  short* h1     = (short*)(ws + off); off += (size_t)LROWS*FFD*2;
  // part_O (attn) and w2part (ffn) are live at disjoint times: share the region
  float* part_O = (float*)(ws + off); off += (size_t)1024*64*64*4;
  float* w2part = part_O;
  float* part_m = (float*)(ws + off); off += (size_t)1024*64*4;
  float* part_l = (float*)(ws + off); off += (size_t)1024*64*4;

  prep_kernel<<<XROWS/4, 256, 0, stream>>>(x, frame_e, media_e, xhat);
  latinit_ln_kernel<<<LROWS, 256, 0, stream>>>(latents, lnl_w, lnl_b, lat, lnlat);
  kvbp_kernel<<<dim3(16, DEPTH), 256, 0, stream>>>(lnm_b, Wkv, kvbp);
  kvbred_kernel<<<DEPTH, 256, 0, stream>>>(kvbp, kvb);
  tcast_all6_kernel<<<DEPTH*2816, 256, 0, stream>>>(
      Wkv, Wq, Wo, W1, W2, lnm_w, Wkvf_a, qkvW_a, Wo_a, W1_a, W2_a);

  for (int i = 0; i < DEPTH; i++) {
    const short* Wkv_f = Wkvf_a + (size_t)i*DIM*DIM;
    const short* qkvW  = qkvW_a + (size_t)i*QKVN*DIM;
    const short* Wo_h  = Wo_a   + (size_t)i*INNER*DIM;
    const short* W1_h  = W1_a   + (size_t)i*DIM*FFD;
    const short* W2_h  = W2_a   + (size_t)i*FFD*DIM;

    gemm_kernel<0,false><<<dim3(LROWS/128, QKVN/128), 256, 0, stream>>>(
        lnlat, qkvW, qkvlat, nullptr, LROWS, QKVN, DIM, DIM);
    gemm256pp_kernel<<<256, 512, 0, stream>>>(xhat, Wkv_f, kvbuf, kvb + i*DIM);
    attn_part_kernel<<<1024, 256, 0, stream>>>(qkvlat, kvbuf, part_O, part_m, part_l);
    attn_combine_kernel<<<128, 256, 0, stream>>>(part_O, part_m, part_l, obuf);
    gemm_kernel<2,false><<<dim3(LROWS/128, DIM/128), 256, 0, stream>>>(
        obuf, Wo_h, lat, nullptr, LROWS, DIM, INNER, INNER);
    ln_kernel<true><<<LROWS, 256, 0, stream>>>(lat, ffln_w + i*DIM, ffln_b + i*DIM, hbuf);
    gemm_kernel<1,true><<<dim3(LROWS/128, FFD/128), 256, 0, stream>>>(
        hbuf, W1_h, h1, b1 + (size_t)i*FFD, LROWS, FFD, DIM, DIM);
    gemm_kernel<4,false><<<dim3(LROWS/128, DIM/128, 4), 256, 0, stream>>>(
        h1, W2_h, w2part, nullptr, LROWS, DIM, DIM, FFD);
    if (i < DEPTH-1)
      w2red_ln_kernel<false><<<LROWS, 256, 0, stream>>>(
          w2part, b2 + (size_t)i*DIM, lat, lnl_w + (i+1)*DIM, lnl_b + (i+1)*DIM, lnlat);
    else
      w2red_ln_kernel<true><<<LROWS, 256, 0, stream>>>(
          w2part, b2 + (size_t)i*DIM, lat, fln_w, fln_b, out);
  }
}

// Round 11
// 1952.836 us; speedup vs baseline: 1.1225x; 1.1225x over previous
//
#include <hip/hip_runtime.h>
#include <math.h>

// PerceiverResampler on MI355X.
// xhat = rownorm(x + frame_emb + media_emb) once (bf16); per-layer LN affine folded
// into Wkv; ALL per-layer weights transpose-cast once upfront (6-layer buffers).
// kv-GEMM: r7-proven grid 8-phase 256x256 pipeline (grid (4,256), XCD swizzle).
// Wo: split-K2 partials + fused {reduce + residual + ffln-LN} kernel.

#define DIM   1024
#define DEPTH 6
#define HEADS 8
#define NLAT  64
#define INNER 512
#define FFD   4096
#define XROWS 65536
#define LROWS 1024
#define NBT   16
#define QKVN  1536

typedef __attribute__((ext_vector_type(8))) short bf16x8;
typedef __attribute__((ext_vector_type(4))) float f32x4;

#define WAITV(n) asm volatile("s_waitcnt vmcnt(" #n ")" ::: "memory")

__device__ __forceinline__ short f2bf(float f) {
  union { float f; unsigned u; } v; v.f = f;
  unsigned r = v.u + 0x7fffu + ((v.u >> 16) & 1u);
  return (short)(r >> 16);
}

__device__ __forceinline__ void gload16(const void* g, void* l) {
  __builtin_amdgcn_global_load_lds(
      (const __attribute__((address_space(1))) unsigned int*)g,
      (__attribute__((address_space(3))) unsigned int*)l, 16, 0, 0);
}

__device__ __forceinline__ f32x4 zero_f4() { f32x4 z; z[0]=0.f; z[1]=0.f; z[2]=0.f; z[3]=0.f; return z; }
__device__ __forceinline__ bf16x8 zero_b8() { bf16x8 z;
#pragma unroll
  for (int e=0;e<8;e++) z[e]=0; return z; }

// ---------------- preprocess ----------------
__global__ __launch_bounds__(256)
void prep_kernel(const float* __restrict__ x, const float* __restrict__ fe,
                 const float* __restrict__ me, short* __restrict__ xhat)
{
  int lane = threadIdx.x & 63;
  int r = blockIdx.x*4 + (threadIdx.x >> 6);
  int f = (r >> 8) & 15, tt = (r >> 12) & 7;
  const float4* xp = (const float4*)(x + (size_t)r*DIM);
  const float4* fp = (const float4*)(fe + (size_t)f*DIM);
  const float4* mp = (const float4*)(me + (size_t)tt*DIM);
  float y[16];
  float s = 0.f, sq = 0.f;
#pragma unroll
  for (int k = 0; k < 4; k++) {
    float4 xv = xp[k*64 + lane], fv = fp[k*64 + lane], mv = mp[k*64 + lane];
    float a0 = xv.x+fv.x+mv.x, a1 = xv.y+fv.y+mv.y, a2 = xv.z+fv.z+mv.z, a3 = xv.w+fv.w+mv.w;
    y[k*4+0]=a0; y[k*4+1]=a1; y[k*4+2]=a2; y[k*4+3]=a3;
    s += a0+a1+a2+a3; sq += a0*a0+a1*a1+a2*a2+a3*a3;
  }
#pragma unroll
  for (int off = 32; off >= 1; off >>= 1) {
    s  += __shfl_xor(s,  off, 64);
    sq += __shfl_xor(sq, off, 64);
  }
  float mean = s * (1.0f/DIM);
  float var  = sq * (1.0f/DIM) - mean*mean;
  float rs = rsqrtf(var + 1e-5f);
  short4* op = (short4*)(xhat + (size_t)r*DIM);
#pragma unroll
  for (int k = 0; k < 4; k++) {
    short4 o;
    o.x = f2bf((y[k*4+0]-mean)*rs); o.y = f2bf((y[k*4+1]-mean)*rs);
    o.z = f2bf((y[k*4+2]-mean)*rs); o.w = f2bf((y[k*4+3]-mean)*rs);
    op[k*64 + lane] = o;
  }
}

// ---------------- block-wide 2-value reduce ----------------
__device__ __forceinline__ void reduce2(float& s, float& sq, float* sh) {
#pragma unroll
  for (int off = 32; off >= 1; off >>= 1) {
    s  += __shfl_xor(s,  off, 64);
    sq += __shfl_xor(sq, off, 64);
  }
  int t = threadIdx.x;
  if ((t & 63) == 0) { sh[(t >> 6)*2] = s; sh[(t >> 6)*2 + 1] = sq; }
  __syncthreads();
  s  = sh[0] + sh[2] + sh[4] + sh[6];
  sq = sh[1] + sh[3] + sh[5] + sh[7];
}

// ---------------- lat init + LN(layer0 lnl); one row per block ----------------
__global__ __launch_bounds__(256)
void latinit_ln_kernel(const float* __restrict__ latents, const float* __restrict__ w,
                       const float* __restrict__ b, float* __restrict__ lat,
                       short* __restrict__ lnlat)
{
  __shared__ float sh[8];
  int r = blockIdx.x, t = threadIdx.x;
  int i = r & 63;
  float4 a = ((const float4*)(latents + (size_t)i*DIM))[t];
  ((float4*)(lat + (size_t)r*DIM))[t] = a;
  float s = a.x+a.y+a.z+a.w;
  float sq = a.x*a.x+a.y*a.y+a.z*a.z+a.w*a.w;
  reduce2(s, sq, sh);
  float mean = s*(1.0f/DIM), var = sq*(1.0f/DIM) - mean*mean;
  float rs = rsqrtf(var + 1e-5f);
  float4 wv = ((const float4*)w)[t], bv = ((const float4*)b)[t];
  short4 o;
  o.x = f2bf((a.x-mean)*rs*wv.x + bv.x);
  o.y = f2bf((a.y-mean)*rs*wv.y + bv.y);
  o.z = f2bf((a.z-mean)*rs*wv.z + bv.z);
  o.w = f2bf((a.w-mean)*rs*wv.w + bv.w);
  ((short4*)(lnlat + (size_t)r*DIM))[t] = o;
}

// ---------------- kvb: split-K partials + reduce ----------------
__global__ __launch_bounds__(256)
void kvbp_kernel(const float* __restrict__ lnm_b, const float* __restrict__ Wkv,
                 float* __restrict__ kvb_part)
{
  int z = blockIdx.x, i = blockIdx.y, t = threadIdx.x;
  const float* W = Wkv + (size_t)i*DIM*DIM;
  const float* bv = lnm_b + (size_t)i*DIM;
  float acc0=0,acc1=0,acc2=0,acc3=0;
  for (int k = z*64; k < z*64+64; k++) {
    float b = bv[k];
    const float* Wr = W + (size_t)k*DIM;
    acc0 += b * Wr[t];       acc1 += b * Wr[t+256];
    acc2 += b * Wr[t+512];   acc3 += b * Wr[t+768];
  }
  float* o = kvb_part + (size_t)(i*16 + z)*DIM;
  o[t] = acc0; o[t+256] = acc1; o[t+512] = acc2; o[t+768] = acc3;
}

__global__ __launch_bounds__(256)
void kvbred_kernel(const float* __restrict__ kvb_part, float* __restrict__ kvb)
{
  int i = blockIdx.x, t = threadIdx.x;
#pragma unroll
  for (int j = 0; j < 4; j++) {
    int col = t + j*256;
    float s = 0.f;
#pragma unroll
    for (int z = 0; z < 16; z++) s += kvb_part[(size_t)(i*16 + z)*DIM + col];
    kvb[i*DIM + col] = s;
  }
}

// ---------------- all-layer transpose-cast (once upfront) ----------------
__global__ __launch_bounds__(256)
void tcast_all6_kernel(const float* __restrict__ Wkv, const float* __restrict__ Wq,
                       const float* __restrict__ Wo, const float* __restrict__ W1,
                       const float* __restrict__ W2, const float* __restrict__ lnm_w,
                       short* __restrict__ Wkvf_a, short* __restrict__ qkvW_a,
                       short* __restrict__ Wo_a, short* __restrict__ W1_a,
                       short* __restrict__ W2_a)
{
  int L = blockIdx.x / 2816;
  int b = blockIdx.x % 2816;
  const float* lWkv = Wkv + (size_t)L*DIM*DIM;
  const float* src; short* dst; const float* fold = nullptr; float scale = 1.0f;
  int K, N, bx, ntx;
  if (b < 256)      { src=lWkv; dst=Wkvf_a + (size_t)L*DIM*DIM; fold=lnm_w + (size_t)L*DIM; K=1024; N=1024; bx=b; ntx=16; }
  else if (b < 384) { src=Wq + (size_t)L*DIM*INNER; dst=qkvW_a + (size_t)L*QKVN*DIM; scale=0.125f; K=1024; N=512; bx=b-256; ntx=8; }
  else if (b < 640) { src=lWkv; dst=qkvW_a + (size_t)L*QKVN*DIM + (size_t)512*1024; K=1024; N=1024; bx=b-384; ntx=16; }
  else if (b < 768) { src=Wo + (size_t)L*INNER*DIM; dst=Wo_a + (size_t)L*INNER*DIM; K=512;  N=1024; bx=b-640; ntx=16; }
  else if (b < 1792){ src=W1 + (size_t)L*DIM*FFD; dst=W1_a + (size_t)L*DIM*FFD; K=1024; N=4096; bx=b-768; ntx=64; }
  else              { src=W2 + (size_t)L*FFD*DIM; dst=W2_a + (size_t)L*FFD*DIM; K=4096; N=1024; bx=b-1792; ntx=16; }
  int n0 = (bx % ntx)*64, k0 = (bx / ntx)*64;
  __shared__ float tile[64][65];
  int t = threadIdx.x;
#pragma unroll
  for (int i = 0; i < 16; i++) {
    int rr = (t >> 6) + i*4, cc = t & 63;
    float v = src[(size_t)(k0+rr)*N + n0 + cc] * scale;
    if (fold) v *= fold[k0 + rr];
    tile[rr][cc] = v;
  }
  __syncthreads();
#pragma unroll
  for (int i = 0; i < 16; i++) {
    int nn = (t >> 6) + i*4, kk = t & 63;
    dst[(size_t)(n0+nn)*K + k0 + kk] = f2bf(tile[kk][nn]);
  }
}

// ---------------- 256x256 8-phase pipelined GEMM (r7 proven) ----------------
__global__ __launch_bounds__(512, 1)
void gemm256p_kernel(const short* __restrict__ A, const short* __restrict__ Bt,
                     short* __restrict__ C, const float* __restrict__ bias,
                     int M, int N, int K)
{
  __shared__ __align__(16) short lds[65536];   // 128 KiB
  char* ldsc = (char*)lds;
  const int t = threadIdx.x, lane = t & 63, wid = t >> 6;
  const int wm = wid >> 2, wn = wid & 3;

  const int nwg = gridDim.x * gridDim.y;
  const int id = blockIdx.y * gridDim.x + blockIdx.x;
  const int work = (id & 7) * (nwg >> 3) + (id >> 3);
  const int bn = work % gridDim.x, bm = work / gridDim.x;
  const int m0 = bm * 256, n0 = bn * 256;

  f32x4 acc[8][4];
#pragma unroll
  for (int m=0;m<8;m++)
#pragma unroll
    for (int n=0;n<4;n++) acc[m][n] = zero_f4();

  const int hK = K << 7;
  const short* pA[2]; const short* pB[2]; int ldst[2];
#pragma unroll
  for (int i = 0; i < 2; i++) {
    int chunk = i*512 + t;
    int rh = chunk >> 3, sl = chunk & 7;
    int ss = sl ^ (rh & 7);
    pA[i] = A + (size_t)(m0 + rh)*K + ss*8;
    pB[i] = Bt + (size_t)(n0 + rh)*K + ss*8;
    ldst[i] = (i*512 + (wid << 6))*16;
  }
  auto stage = [&](int tile, int mat, int half) {
    char* dbase = ldsc + mat*65536 + (tile & 1)*32768 + half*16384;
#pragma unroll
    for (int i = 0; i < 2; i++) {
      const short* src = (mat ? pB[i] : pA[i]) + half*hK + tile*64;
      gload16(src, dbase + ldst[i]);
    }
  };

  const int sk0 = (((lane >> 4)    ) ^ (lane & 7)) * 16;
  const int sk1 = ((4 + (lane >> 4)) ^ (lane & 7)) * 16;
  const int rowb = (lane & 15) * 128;
  const char* aB[2] = { ldsc + wm*16384 + rowb + sk0, ldsc + wm*16384 + rowb + sk1 };
  const char* bB[2] = { ldsc + 65536 + wn*8192 + rowb + sk0, ldsc + 65536 + wn*8192 + rowb + sk1 };

#define PHASE(BUF, Q, STAGE_STMT, GATE) do {                               \
    if ((Q) == 0) {                                                        \
      _Pragma("unroll") for (int n_=0;n_<4;n_++)                           \
        _Pragma("unroll") for (int k_=0;k_<2;k_++)                         \
          bfr[n_][k_] = *(const bf16x8*)(bB[k_] + (BUF)*32768 + n_*2048);  \
    }                                                                      \
    _Pragma("unroll") for (int i_=0;i_<2;i_++)                             \
      _Pragma("unroll") for (int k_=0;k_<2;k_++)                           \
        afr[i_][k_] = *(const bf16x8*)(aB[k_] + (BUF)*32768 + (2*(Q)+i_)*2048); \
    STAGE_STMT;                                                            \
    GATE;                                                                  \
    __builtin_amdgcn_sched_barrier(0);                                     \
    __builtin_amdgcn_s_barrier();                                          \
    asm volatile("s_waitcnt lgkmcnt(0)" ::: "memory");                     \
    __builtin_amdgcn_sched_barrier(0);                                     \
    __builtin_amdgcn_s_setprio(1);                                         \
    _Pragma("unroll") for (int k_=0;k_<2;k_++)                             \
      _Pragma("unroll") for (int i_=0;i_<2;i_++)                           \
        _Pragma("unroll") for (int n_=0;n_<4;n_++)                         \
          acc[2*(Q)+i_][n_] = __builtin_amdgcn_mfma_f32_16x16x32_bf16(     \
              afr[i_][k_], bfr[n_][k_], acc[2*(Q)+i_][n_], 0, 0, 0);       \
    __builtin_amdgcn_s_setprio(0);                                         \
    __builtin_amdgcn_sched_barrier(0);                                     \
    __builtin_amdgcn_s_barrier();                                          \
  } while (0)

  const int NU = K >> 7;
  stage(0, 0, 0); stage(0, 0, 1); stage(0, 1, 0); stage(0, 1, 1);
  stage(1, 1, 0); stage(1, 1, 1);
  WAITV(4);
  __builtin_amdgcn_sched_barrier(0);
  __builtin_amdgcn_s_barrier();

#pragma unroll 1
  for (int u = 0; u < NU; ++u) {
    const int t0 = 2*u, t1 = t0 + 1;
    const bool more = (u + 1 < NU);
    bf16x8 bfr[4][2], afr[2][2];
    PHASE(0, 0, stage(t1, 0, 0),               (void)0);
    PHASE(0, 1, stage(t1, 0, 1),               (void)0);
    PHASE(0, 2, if (more) stage(t0+2, 1, 0),   (void)0);
    PHASE(0, 3, if (more) stage(t0+2, 1, 1),   if (more) { WAITV(4); } else { WAITV(0); });
    PHASE(1, 0, if (more) stage(t0+2, 0, 0),   (void)0);
    PHASE(1, 1, if (more) stage(t0+2, 0, 1),   (void)0);
    PHASE(1, 2, if (more) stage(t1+2, 1, 0),   (void)0);
    PHASE(1, 3, if (more) stage(t1+2, 1, 1),   if (more) { WAITV(4); });
  }
#undef PHASE

  const int g = lane >> 4;
#pragma unroll
  for (int m=0;m<8;m++) {
#pragma unroll
    for (int n=0;n<4;n++) {
#pragma unroll
      for (int r=0;r<4;r++) {
        int mm = m0 + wm*128 + m*16 + g*4 + r;
        int nn = n0 + wn*64 + n*16 + (lane & 15);
        float v = acc[m][n][r] + bias[nn];
        C[(size_t)mm*N + nn] = f2bf(v);
      }
    }
  }
}

// ---------------- 128x128 GEMM (small shapes) ----------------
// EPI: 0 bf16 store, 1 gelu+bf16, 4 f32 partial store (split-K z)
template<int EPI, bool HAS_BIAS>
__global__ __launch_bounds__(256, 2)
void gemm_kernel(const short* __restrict__ A, const short* __restrict__ Bt,
                 void* __restrict__ Cout, const float* __restrict__ bias,
                 int M, int N, int K, int ldk)
{
  __shared__ __align__(16) short As[128*64];
  __shared__ __align__(16) short Bs[128*64];
  const int t = threadIdx.x;
  const int lane = t & 63, w = t >> 6;
  const int m0 = blockIdx.x * 128, n0 = blockIdx.y * 128;
  const int wr = (w >> 1) * 64, wc = (w & 1) * 64;
  const short* Ap = A + (size_t)blockIdx.z * K;
  const short* Btp = Bt + (size_t)blockIdx.z * K;

  f32x4 acc[4][4];
#pragma unroll
  for (int i=0;i<4;i++)
#pragma unroll
    for (int j=0;j<4;j++) acc[i][j] = zero_f4();

  for (int kt = 0; kt < K; kt += 64) {
#pragma unroll
    for (int i = 0; i < 4; i++) {
      int chunk = i*256 + t;
      int row = chunk >> 3, slot = chunk & 7;
      int ss = slot ^ (row & 7);
      gload16(Ap + (size_t)(m0 + row)*ldk + kt + ss*8,
              (char*)As + (i*256 + (w<<6))*16);
    }
#pragma unroll
    for (int i = 0; i < 4; i++) {
      int chunk = i*256 + t;
      int row = chunk >> 3, slot = chunk & 7;
      int ss = slot ^ (row & 7);
      gload16(Btp + (size_t)(n0 + row)*ldk + kt + ss*8,
              (char*)Bs + (i*256 + (w<<6))*16);
    }
    __syncthreads();

#pragma unroll
    for (int ks = 0; ks < 2; ks++) {
      bf16x8 af[4], bfr[4];
#pragma unroll
      for (int i=0;i<4;i++) {
        int row = wr + i*16 + (lane & 15);
        int slot = (ks*4 + (lane >> 4)) ^ (row & 7);
        af[i] = *(const bf16x8*)((const char*)As + row*128 + slot*16);
        int nrow = wc + i*16 + (lane & 15);
        int nslot = (ks*4 + (lane >> 4)) ^ (nrow & 7);
        bfr[i] = *(const bf16x8*)((const char*)Bs + nrow*128 + nslot*16);
      }
#pragma unroll
      for (int i=0;i<4;i++)
#pragma unroll
        for (int j=0;j<4;j++)
          acc[i][j] = __builtin_amdgcn_mfma_f32_16x16x32_bf16(af[i], bfr[j], acc[i][j], 0, 0, 0);
    }
    __syncthreads();
  }

  const int g = lane >> 4;
#pragma unroll
  for (int i=0;i<4;i++) {
#pragma unroll
    for (int j=0;j<4;j++) {
#pragma unroll
      for (int r=0;r<4;r++) {
        int m = m0 + wr + i*16 + g*4 + r;
        int n = n0 + wc + j*16 + (lane & 15);
        float v = acc[i][j][r];
        if (EPI == 0) {
          if (HAS_BIAS) v += bias[n];
          ((short*)Cout)[(size_t)m*N + n] = f2bf(v);
        } else if (EPI == 1) {
          if (HAS_BIAS) v += bias[n];
          float gl = 0.5f * v * (1.0f + erff(v * 0.70710678f));
          ((short*)Cout)[(size_t)m*N + n] = f2bf(gl);
        } else {
          ((float*)Cout)[(size_t)blockIdx.z*M*N + (size_t)m*N + n] = v;
        }
      }
    }
  }
}

// ---------------- Wo reduce (2 partials) + residual + ffln LN -> hbuf ----------------
__global__ __launch_bounds__(256)
void wored_ffln_kernel(const float* __restrict__ part, float* __restrict__ lat,
                       const float* __restrict__ w, const float* __restrict__ bb,
                       short* __restrict__ hbuf)
{
  __shared__ float sh[8];
  int r = blockIdx.x, t = threadIdx.x;
  int idx = r*256 + t;
  float4 a = ((float4*)lat)[idx];
  float4 p0 = ((const float4*)part)[idx];
  float4 p1 = ((const float4*)(part + (size_t)LROWS*DIM))[idx];
  a.x += p0.x + p1.x; a.y += p0.y + p1.y; a.z += p0.z + p1.z; a.w += p0.w + p1.w;
  ((float4*)lat)[idx] = a;
  float s = a.x+a.y+a.z+a.w;
  float sq = a.x*a.x+a.y*a.y+a.z*a.z+a.w*a.w;
  reduce2(s, sq, sh);
  float mean = s*(1.0f/DIM), var = sq*(1.0f/DIM) - mean*mean;
  float rs = rsqrtf(var + 1e-5f);
  float4 wv = ((const float4*)w)[t], bv = ((const float4*)bb)[t];
  short4 o;
  o.x = f2bf((a.x-mean)*rs*wv.x + bv.x);
  o.y = f2bf((a.y-mean)*rs*wv.y + bv.y);
  o.z = f2bf((a.z-mean)*rs*wv.z + bv.z);
  o.w = f2bf((a.w-mean)*rs*wv.w + bv.w);
  ((short4*)(hbuf + (size_t)r*DIM))[t] = o;
}

// ---------------- W2 split-K reduce + residual + LN(next lnl or final fln) ----------------
template<bool LAST>
__global__ __launch_bounds__(256)
void w2red_ln_kernel(const float* __restrict__ part, const float* __restrict__ b2,
                     float* __restrict__ lat, const float* __restrict__ w,
                     const float* __restrict__ bb, void* __restrict__ dst)
{
  __shared__ float sh[8];
  int r = blockIdx.x, t = threadIdx.x;
  int idx = r*256 + t;
  float4 a = ((float4*)lat)[idx];
  float4 b4 = ((const float4*)b2)[t];
  a.x += b4.x; a.y += b4.y; a.z += b4.z; a.w += b4.w;
#pragma unroll
  for (int z = 0; z < 4; z++) {
    float4 p = ((const float4*)(part + (size_t)z*LROWS*DIM))[idx];
    a.x += p.x; a.y += p.y; a.z += p.z; a.w += p.w;
  }
  ((float4*)lat)[idx] = a;
  float s = a.x+a.y+a.z+a.w;
  float sq = a.x*a.x+a.y*a.y+a.z*a.z+a.w*a.w;
  reduce2(s, sq, sh);
  float mean = s*(1.0f/DIM), var = sq*(1.0f/DIM) - mean*mean;
  float rs = rsqrtf(var + 1e-5f);
  float4 wv = ((const float4*)w)[t], bv = ((const float4*)bb)[t];
  float o0 = (a.x-mean)*rs*wv.x + bv.x;
  float o1 = (a.y-mean)*rs*wv.y + bv.y;
  float o2 = (a.z-mean)*rs*wv.z + bv.z;
  float o3 = (a.w-mean)*rs*wv.w + bv.w;
  if (LAST) {
    float4 o; o.x=o0; o.y=o1; o.z=o2; o.w=o3;
    ((float4*)((float*)dst + (size_t)r*DIM))[t] = o;
  } else {
    short4 o; o.x=f2bf(o0); o.y=f2bf(o1); o.z=f2bf(o2); o.w=f2bf(o3);
    ((short4*)((short*)dst + (size_t)r*DIM))[t] = o;
  }
}

// ---------------- attention pass 1: split-K flash, register softmax ----------------
__global__ __launch_bounds__(256, 2)
void attn_part_kernel(const short* __restrict__ qkvlat, const short* __restrict__ kvbuf,
                      float* __restrict__ part_O, float* __restrict__ part_m,
                      float* __restrict__ part_l)
{
  __shared__ __align__(16) short q_sh[64*64];
  __shared__ __align__(16) short K_sh[128*64];
  __shared__ __align__(16) short VT_sh[64*128];
  __shared__ __align__(16) short P_sh[64*132];

  const int t = threadIdx.x, lane = t & 63, w = t >> 6;
  const int bid = blockIdx.x;
  const int s = bid & 7, bh = bid >> 3;
  const int h = bh & 7, bt = bh >> 3;

  {
    const short* qsrc = qkvlat + (size_t)(bt*64)*QKVN + h*64;
#pragma unroll
    for (int i = 0; i < 2; i++) {
      int chunk = i*256 + t;
      int row = chunk >> 3, slot = chunk & 7;
      gload16(qsrc + (size_t)row*QKVN + ((slot ^ (row & 7))*8),
              (char*)q_sh + (i*256 + (w<<6))*16);
    }
  }

  float m_run[4], l_run[4];
#pragma unroll
  for (int r=0;r<4;r++){ m_run[r] = -1e30f; l_run[r] = 0.f; }
  f32x4 oacc[4];
#pragma unroll
  for (int j=0;j<4;j++) oacc[j] = zero_f4();

  const int nch = (s == 7) ? 5 : 4;
  for (int c5 = 0; c5 < nch; c5++) {
    __syncthreads();
    const bool isLat = (c5 == 4);
    const int jv = isLat ? 4 : 8;
    const short* kbase; int kstride, valid;
    if (!isLat) {
      kbase = kvbuf + ((size_t)bt*4096 + (s*4 + c5)*128)*DIM + h*64;
      kstride = DIM; valid = 128;
    } else {
      kbase = qkvlat + (size_t)(bt*64)*QKVN + 512 + h*64;
      kstride = QKVN; valid = 64;
    }
    const short* vbase = kbase + 512;

#pragma unroll
    for (int i = 0; i < 4; i++) {
      int chunk = i*256 + t;
      int row = chunk >> 3, slot = chunk & 7;
      gload16(kbase + (size_t)row*kstride + ((slot ^ (row & 7))*8),
              (char*)K_sh + (i*256 + (w<<6))*16);
    }
#pragma unroll
    for (int i = 0; i < 4; i++) {
      int c = i*256 + t;
      int row = c >> 3, slot = c & 7;
      bf16x8 v = (row < valid) ? *(const bf16x8*)(vbase + (size_t)row*kstride + slot*8) : zero_b8();
      int kslot = row >> 3;
#pragma unroll
      for (int e=0;e<8;e++) {
        int dh = slot*8 + e;
        VT_sh[dh*128 + ((kslot ^ (dh & 7))*8) + (row & 7)] = v[e];
      }
    }
    __syncthreads();

    f32x4 sacc[8];
#pragma unroll
    for (int j=0;j<8;j++) sacc[j] = zero_f4();
#pragma unroll
    for (int ks=0; ks<2; ks++) {
      int arow = w*16 + (lane & 15);
      int aslot = (ks*4 + (lane >> 4)) ^ (arow & 7);
      bf16x8 af = *(const bf16x8*)((const char*)q_sh + arow*128 + aslot*16);
#pragma unroll
      for (int j=0;j<8;j++) {
        int brow = j*16 + (lane & 15);
        int bslot = (ks*4 + (lane >> 4)) ^ (brow & 7);
        bf16x8 bv = *(const bf16x8*)((const char*)K_sh + brow*128 + bslot*16);
        sacc[j] = __builtin_amdgcn_mfma_f32_16x16x32_bf16(af, bv, sacc[j], 0, 0, 0);
      }
    }

    float mx[4];
#pragma unroll
    for (int r=0;r<4;r++) mx[r] = -1e30f;
#pragma unroll
    for (int j=0;j<8;j++) {
      if (j < jv) {
#pragma unroll
        for (int r=0;r<4;r++) mx[r] = fmaxf(mx[r], sacc[j][r]);
      }
    }
#pragma unroll
    for (int m2=1; m2<16; m2<<=1) {
#pragma unroll
      for (int r=0;r<4;r++) mx[r] = fmaxf(mx[r], __shfl_xor(mx[r], m2, 64));
    }
    float alpha[4], rowsum[4];
#pragma unroll
    for (int r=0;r<4;r++) {
      float nm = fmaxf(m_run[r], mx[r]);
      alpha[r] = __expf(m_run[r] - nm);
      m_run[r] = nm;
      rowsum[r] = 0.f;
    }
#pragma unroll
    for (int j=0;j<8;j++) {
#pragma unroll
      for (int r=0;r<4;r++) {
        float p = 0.f;
        if (j < jv) { p = __expf(sacc[j][r] - m_run[r]); rowsum[r] += p; }
        P_sh[(w*16 + (lane>>4)*4 + r)*132 + j*16 + (lane & 15)] = f2bf(p);
      }
    }
#pragma unroll
    for (int m2=1; m2<16; m2<<=1) {
#pragma unroll
      for (int r=0;r<4;r++) rowsum[r] += __shfl_xor(rowsum[r], m2, 64);
    }
#pragma unroll
    for (int r=0;r<4;r++) l_run[r] = l_run[r]*alpha[r] + rowsum[r];
#pragma unroll
    for (int j=0;j<4;j++) {
#pragma unroll
      for (int r=0;r<4;r++) oacc[j][r] *= alpha[r];
    }
    __syncthreads();

#pragma unroll
    for (int ks=0; ks<4; ks++) {
      int prow = w*16 + (lane & 15);
      bf16x8 af = *(const bf16x8*)((const char*)P_sh + prow*264 + ks*64 + (lane >> 4)*16);
#pragma unroll
      for (int j=0;j<4;j++) {
        int dh = j*16 + (lane & 15);
        int kslot = (ks*4 + (lane >> 4)) ^ (dh & 7);
        bf16x8 bv = *(const bf16x8*)((const char*)VT_sh + dh*256 + kslot*16);
        oacc[j] = __builtin_amdgcn_mfma_f32_16x16x32_bf16(af, bv, oacc[j], 0, 0, 0);
      }
    }
  }

  {
    float* Ob = part_O + (size_t)bid*4096;
    int rbase = w*16 + (lane>>4)*4;
#pragma unroll
    for (int j=0;j<4;j++) {
#pragma unroll
      for (int r=0;r<4;r++)
        Ob[(rbase + r)*64 + j*16 + (lane & 15)] = oacc[j][r];
    }
    if ((lane & 15) == 0) {
#pragma unroll
      for (int r=0;r<4;r++) {
        part_m[(size_t)bid*64 + rbase + r] = m_run[r];
        part_l[(size_t)bid*64 + rbase + r] = l_run[r];
      }
    }
  }
}

// ---------------- attention pass 2 ----------------
__global__ __launch_bounds__(256)
void attn_combine_kernel(const float* __restrict__ part_O, const float* __restrict__ part_m,
                         const float* __restrict__ part_l, short* __restrict__ obuf)
{
  int bh = blockIdx.x, t = threadIdx.x;
  int q = t >> 2, c0 = (t & 3) * 16;
  int bt = bh >> 3, h = bh & 7;
  float m8[8], w8[8];
  float mmax = -1e30f;
#pragma unroll
  for (int s=0;s<8;s++) { m8[s] = part_m[(size_t)(bh*8+s)*64 + q]; mmax = fmaxf(mmax, m8[s]); }
  float lt = 0.f;
#pragma unroll
  for (int s=0;s<8;s++) { w8[s] = __expf(m8[s] - mmax); lt += w8[s] * part_l[(size_t)(bh*8+s)*64 + q]; }
  float inv = 1.0f / lt;
  float4 acc[4];
#pragma unroll
  for (int u=0;u<4;u++) { acc[u].x=0.f; acc[u].y=0.f; acc[u].z=0.f; acc[u].w=0.f; }
#pragma unroll
  for (int s=0;s<8;s++) {
    const float4* Ob = (const float4*)(part_O + ((size_t)(bh*8+s)*64 + q)*64 + c0);
#pragma unroll
    for (int u=0;u<4;u++) {
      float4 v = Ob[u];
      acc[u].x += w8[s]*v.x; acc[u].y += w8[s]*v.y;
      acc[u].z += w8[s]*v.z; acc[u].w += w8[s]*v.w;
    }
  }
  short* ob = obuf + (size_t)(bt*64 + q)*INNER + h*64 + c0;
#pragma unroll
  for (int u=0;u<4;u++) {
    short4 o;
    o.x = f2bf(acc[u].x*inv); o.y = f2bf(acc[u].y*inv);
    o.z = f2bf(acc[u].z*inv); o.w = f2bf(acc[u].w*inv);
    ((short4*)ob)[u] = o;
  }
}

// ---------------- launch ----------------
extern "C" void kernel_launch(void* const* d_in, const int* in_sizes, int n_in,
                              void* d_out, int out_size, void* d_ws, size_t ws_size,
                              hipStream_t stream)
{
  (void)in_sizes; (void)n_in; (void)out_size; (void)ws_size;
  const float* x        = (const float*)d_in[0];
  const float* latents  = (const float*)d_in[1];
  const float* frame_e  = (const float*)d_in[2];
  const float* media_e  = (const float*)d_in[3];
  const float* lnm_w    = (const float*)d_in[4];
  const float* lnm_b    = (const float*)d_in[5];
  const float* lnl_w    = (const float*)d_in[6];
  const float* lnl_b    = (const float*)d_in[7];
  const float* Wq       = (const float*)d_in[8];
  const float* Wkv      = (const float*)d_in[9];
  const float* Wo       = (const float*)d_in[10];
  const float* ffln_w   = (const float*)d_in[11];
  const float* ffln_b   = (const float*)d_in[12];
  const float* W1       = (const float*)d_in[13];
  const float* b1       = (const float*)d_in[14];
  const float* W2       = (const float*)d_in[15];
  const float* b2       = (const float*)d_in[16];
  const float* fln_w    = (const float*)d_in[17];
  const float* fln_b    = (const float*)d_in[18];
  float* out = (float*)d_out;

  char* ws = (char*)d_ws;
  size_t off = 0;
  short* xhat   = (short*)(ws + off); off += (size_t)XROWS*DIM*2;
  short* kvbuf  = (short*)(ws + off); off += (size_t)XROWS*DIM*2;
  short* Wkvf_a = (short*)(ws + off); off += (size_t)DEPTH*DIM*DIM*2;
  short* qkvW_a = (short*)(ws + off); off += (size_t)DEPTH*QKVN*DIM*2;
  short* Wo_a   = (short*)(ws + off); off += (size_t)DEPTH*INNER*DIM*2;
  short* W1_a   = (short*)(ws + off); off += (size_t)DEPTH*DIM*FFD*2;
  short* W2_a   = (short*)(ws + off); off += (size_t)DEPTH*FFD*DIM*2;
  float* kvb    = (float*)(ws + off); off += (size_t)DEPTH*DIM*4;
  float* kvbp   = (float*)(ws + off); off += (size_t)DEPTH*16*DIM*4;
  float* lat    = (float*)(ws + off); off += (size_t)LROWS*DIM*4;
  short* lnlat  = (short*)(ws + off); off += (size_t)LROWS*DIM*2;
  short* qkvlat = (short*)(ws + off); off += (size_t)LROWS*QKVN*2;
  short* obuf   = (short*)(ws + off); off += (size_t)LROWS*INNER*2;
  short* hbuf   = (short*)(ws + off); off += (size_t)LROWS*DIM*2;
  short* h1     = (short*)(ws + off); off += (size_t)LROWS*FFD*2;
  float* wopart = (float*)(ws + off); off += (size_t)2*LROWS*DIM*4;
  // part_O (attn) and w2part (ffn) live at disjoint times: share the region
  float* part_O = (float*)(ws + off); off += (size_t)1024*64*64*4;
  float* w2part = part_O;
  float* part_m = (float*)(ws + off); off += (size_t)1024*64*4;
  float* part_l = (float*)(ws + off); off += (size_t)1024*64*4;

  prep_kernel<<<XROWS/4, 256, 0, stream>>>(x, frame_e, media_e, xhat);
  latinit_ln_kernel<<<LROWS, 256, 0, stream>>>(latents, lnl_w, lnl_b, lat, lnlat);
  kvbp_kernel<<<dim3(16, DEPTH), 256, 0, stream>>>(lnm_b, Wkv, kvbp);
  kvbred_kernel<<<DEPTH, 256, 0, stream>>>(kvbp, kvb);
  tcast_all6_kernel<<<DEPTH*2816, 256, 0, stream>>>(
      Wkv, Wq, Wo, W1, W2, lnm_w, Wkvf_a, qkvW_a, Wo_a, W1_a, W2_a);

  for (int i = 0; i < DEPTH; i++) {
    const short* Wkv_f = Wkvf_a + (size_t)i*DIM*DIM;
    const short* qkvW  = qkvW_a + (size_t)i*QKVN*DIM;
    const short* Wo_h  = Wo_a   + (size_t)i*INNER*DIM;
    const short* W1_h  = W1_a   + (size_t)i*DIM*FFD;
    const short* W2_h  = W2_a   + (size_t)i*FFD*DIM;

    gemm_kernel<0,false><<<dim3(LROWS/128, QKVN/128), 256, 0, stream>>>(
        lnlat, qkvW, qkvlat, nullptr, LROWS, QKVN, DIM, DIM);
    gemm256p_kernel<<<dim3(DIM/256, XROWS/256), 512, 0, stream>>>(
        xhat, Wkv_f, kvbuf, kvb + i*DIM, XROWS, DIM, DIM);
    attn_part_kernel<<<1024, 256, 0, stream>>>(qkvlat, kvbuf, part_O, part_m, part_l);
    attn_combine_kernel<<<128, 256, 0, stream>>>(part_O, part_m, part_l, obuf);
    gemm_kernel<4,false><<<dim3(LROWS/128, DIM/128, 2), 256, 0, stream>>>(
        obuf, Wo_h, wopart, nullptr, LROWS, DIM, 256, INNER);
    wored_ffln_kernel<<<LROWS, 256, 0, stream>>>(
        wopart, lat, ffln_w + i*DIM, ffln_b + i*DIM, hbuf);
    gemm_kernel<1,true><<<dim3(LROWS/128, FFD/128), 256, 0, stream>>>(
        hbuf, W1_h, h1, b1 + (size_t)i*FFD, LROWS, FFD, DIM, DIM);
    gemm_kernel<4,false><<<dim3(LROWS/128, DIM/128, 4), 256, 0, stream>>>(
        h1, W2_h, w2part, nullptr, LROWS, DIM, DIM, FFD);
    if (i < DEPTH-1)
      w2red_ln_kernel<false><<<LROWS, 256, 0, stream>>>(
          w2part, b2 + (size_t)i*DIM, lat, lnl_w + (i+1)*DIM, lnl_b + (i+1)*DIM, lnlat);
    else
      w2red_ln_kernel<true><<<LROWS, 256, 0, stream>>>(
          w2part, b2 + (size_t)i*DIM, lat, fln_w, fln_b, out);
  }
}

// Round 12
// 1925.381 us; speedup vs baseline: 1.1385x; 1.0143x over previous
//
#include <hip/hip_runtime.h>
#include <math.h>

// PerceiverResampler on MI355X.
// xhat = rownorm(x + frame_emb + media_emb) once (bf16); per-layer LN affine folded
// into Wkv; ALL per-layer weights transpose-cast once upfront (6-layer buffers).
// kv-GEMM: r7-proven grid 8-phase 256x256 pipeline (grid (4,256), XCD swizzle).
// Attention: 4-way split-K flash (512 blocks), VT staged with rotate-by-(dh&0x78)
// swizzle (write conflicts 16-way -> 2-way). Wo split-K2 + fused reduce/LN kernels.

#define DIM   1024
#define DEPTH 6
#define HEADS 8
#define NLAT  64
#define INNER 512
#define FFD   4096
#define XROWS 65536
#define LROWS 1024
#define NBT   16
#define QKVN  1536

typedef __attribute__((ext_vector_type(8))) short bf16x8;
typedef __attribute__((ext_vector_type(4))) float f32x4;

#define WAITV(n) asm volatile("s_waitcnt vmcnt(" #n ")" ::: "memory")

__device__ __forceinline__ short f2bf(float f) {
  union { float f; unsigned u; } v; v.f = f;
  unsigned r = v.u + 0x7fffu + ((v.u >> 16) & 1u);
  return (short)(r >> 16);
}

__device__ __forceinline__ void gload16(const void* g, void* l) {
  __builtin_amdgcn_global_load_lds(
      (const __attribute__((address_space(1))) unsigned int*)g,
      (__attribute__((address_space(3))) unsigned int*)l, 16, 0, 0);
}

__device__ __forceinline__ f32x4 zero_f4() { f32x4 z; z[0]=0.f; z[1]=0.f; z[2]=0.f; z[3]=0.f; return z; }
__device__ __forceinline__ bf16x8 zero_b8() { bf16x8 z;
#pragma unroll
  for (int e=0;e<8;e++) z[e]=0; return z; }

// ---------------- preprocess ----------------
__global__ __launch_bounds__(256)
void prep_kernel(const float* __restrict__ x, const float* __restrict__ fe,
                 const float* __restrict__ me, short* __restrict__ xhat)
{
  int lane = threadIdx.x & 63;
  int r = blockIdx.x*4 + (threadIdx.x >> 6);
  int f = (r >> 8) & 15, tt = (r >> 12) & 7;
  const float4* xp = (const float4*)(x + (size_t)r*DIM);
  const float4* fp = (const float4*)(fe + (size_t)f*DIM);
  const float4* mp = (const float4*)(me + (size_t)tt*DIM);
  float y[16];
  float s = 0.f, sq = 0.f;
#pragma unroll
  for (int k = 0; k < 4; k++) {
    float4 xv = xp[k*64 + lane], fv = fp[k*64 + lane], mv = mp[k*64 + lane];
    float a0 = xv.x+fv.x+mv.x, a1 = xv.y+fv.y+mv.y, a2 = xv.z+fv.z+mv.z, a3 = xv.w+fv.w+mv.w;
    y[k*4+0]=a0; y[k*4+1]=a1; y[k*4+2]=a2; y[k*4+3]=a3;
    s += a0+a1+a2+a3; sq += a0*a0+a1*a1+a2*a2+a3*a3;
  }
#pragma unroll
  for (int off = 32; off >= 1; off >>= 1) {
    s  += __shfl_xor(s,  off, 64);
    sq += __shfl_xor(sq, off, 64);
  }
  float mean = s * (1.0f/DIM);
  float var  = sq * (1.0f/DIM) - mean*mean;
  float rs = rsqrtf(var + 1e-5f);
  short4* op = (short4*)(xhat + (size_t)r*DIM);
#pragma unroll
  for (int k = 0; k < 4; k++) {
    short4 o;
    o.x = f2bf((y[k*4+0]-mean)*rs); o.y = f2bf((y[k*4+1]-mean)*rs);
    o.z = f2bf((y[k*4+2]-mean)*rs); o.w = f2bf((y[k*4+3]-mean)*rs);
    op[k*64 + lane] = o;
  }
}

// ---------------- block-wide 2-value reduce ----------------
__device__ __forceinline__ void reduce2(float& s, float& sq, float* sh) {
#pragma unroll
  for (int off = 32; off >= 1; off >>= 1) {
    s  += __shfl_xor(s,  off, 64);
    sq += __shfl_xor(sq, off, 64);
  }
  int t = threadIdx.x;
  if ((t & 63) == 0) { sh[(t >> 6)*2] = s; sh[(t >> 6)*2 + 1] = sq; }
  __syncthreads();
  s  = sh[0] + sh[2] + sh[4] + sh[6];
  sq = sh[1] + sh[3] + sh[5] + sh[7];
}

// ---------------- lat init + LN(layer0 lnl); one row per block ----------------
__global__ __launch_bounds__(256)
void latinit_ln_kernel(const float* __restrict__ latents, const float* __restrict__ w,
                       const float* __restrict__ b, float* __restrict__ lat,
                       short* __restrict__ lnlat)
{
  __shared__ float sh[8];
  int r = blockIdx.x, t = threadIdx.x;
  int i = r & 63;
  float4 a = ((const float4*)(latents + (size_t)i*DIM))[t];
  ((float4*)(lat + (size_t)r*DIM))[t] = a;
  float s = a.x+a.y+a.z+a.w;
  float sq = a.x*a.x+a.y*a.y+a.z*a.z+a.w*a.w;
  reduce2(s, sq, sh);
  float mean = s*(1.0f/DIM), var = sq*(1.0f/DIM) - mean*mean;
  float rs = rsqrtf(var + 1e-5f);
  float4 wv = ((const float4*)w)[t], bv = ((const float4*)b)[t];
  short4 o;
  o.x = f2bf((a.x-mean)*rs*wv.x + bv.x);
  o.y = f2bf((a.y-mean)*rs*wv.y + bv.y);
  o.z = f2bf((a.z-mean)*rs*wv.z + bv.z);
  o.w = f2bf((a.w-mean)*rs*wv.w + bv.w);
  ((short4*)(lnlat + (size_t)r*DIM))[t] = o;
}

// ---------------- kvb: split-K partials + reduce ----------------
__global__ __launch_bounds__(256)
void kvbp_kernel(const float* __restrict__ lnm_b, const float* __restrict__ Wkv,
                 float* __restrict__ kvb_part)
{
  int z = blockIdx.x, i = blockIdx.y, t = threadIdx.x;
  const float* W = Wkv + (size_t)i*DIM*DIM;
  const float* bv = lnm_b + (size_t)i*DIM;
  float acc0=0,acc1=0,acc2=0,acc3=0;
  for (int k = z*64; k < z*64+64; k++) {
    float b = bv[k];
    const float* Wr = W + (size_t)k*DIM;
    acc0 += b * Wr[t];       acc1 += b * Wr[t+256];
    acc2 += b * Wr[t+512];   acc3 += b * Wr[t+768];
  }
  float* o = kvb_part + (size_t)(i*16 + z)*DIM;
  o[t] = acc0; o[t+256] = acc1; o[t+512] = acc2; o[t+768] = acc3;
}

__global__ __launch_bounds__(256)
void kvbred_kernel(const float* __restrict__ kvb_part, float* __restrict__ kvb)
{
  int i = blockIdx.x, t = threadIdx.x;
#pragma unroll
  for (int j = 0; j < 4; j++) {
    int col = t + j*256;
    float s = 0.f;
#pragma unroll
    for (int z = 0; z < 16; z++) s += kvb_part[(size_t)(i*16 + z)*DIM + col];
    kvb[i*DIM + col] = s;
  }
}

// ---------------- all-layer transpose-cast (once upfront) ----------------
__global__ __launch_bounds__(256)
void tcast_all6_kernel(const float* __restrict__ Wkv, const float* __restrict__ Wq,
                       const float* __restrict__ Wo, const float* __restrict__ W1,
                       const float* __restrict__ W2, const float* __restrict__ lnm_w,
                       short* __restrict__ Wkvf_a, short* __restrict__ qkvW_a,
                       short* __restrict__ Wo_a, short* __restrict__ W1_a,
                       short* __restrict__ W2_a)
{
  int L = blockIdx.x / 2816;
  int b = blockIdx.x % 2816;
  const float* lWkv = Wkv + (size_t)L*DIM*DIM;
  const float* src; short* dst; const float* fold = nullptr; float scale = 1.0f;
  int K, N, bx, ntx;
  if (b < 256)      { src=lWkv; dst=Wkvf_a + (size_t)L*DIM*DIM; fold=lnm_w + (size_t)L*DIM; K=1024; N=1024; bx=b; ntx=16; }
  else if (b < 384) { src=Wq + (size_t)L*DIM*INNER; dst=qkvW_a + (size_t)L*QKVN*DIM; scale=0.125f; K=1024; N=512; bx=b-256; ntx=8; }
  else if (b < 640) { src=lWkv; dst=qkvW_a + (size_t)L*QKVN*DIM + (size_t)512*1024; K=1024; N=1024; bx=b-384; ntx=16; }
  else if (b < 768) { src=Wo + (size_t)L*INNER*DIM; dst=Wo_a + (size_t)L*INNER*DIM; K=512;  N=1024; bx=b-640; ntx=16; }
  else if (b < 1792){ src=W1 + (size_t)L*DIM*FFD; dst=W1_a + (size_t)L*DIM*FFD; K=1024; N=4096; bx=b-768; ntx=64; }
  else              { src=W2 + (size_t)L*FFD*DIM; dst=W2_a + (size_t)L*FFD*DIM; K=4096; N=1024; bx=b-1792; ntx=16; }
  int n0 = (bx % ntx)*64, k0 = (bx / ntx)*64;
  __shared__ float tile[64][65];
  int t = threadIdx.x;
#pragma unroll
  for (int i = 0; i < 16; i++) {
    int rr = (t >> 6) + i*4, cc = t & 63;
    float v = src[(size_t)(k0+rr)*N + n0 + cc] * scale;
    if (fold) v *= fold[k0 + rr];
    tile[rr][cc] = v;
  }
  __syncthreads();
#pragma unroll
  for (int i = 0; i < 16; i++) {
    int nn = (t >> 6) + i*4, kk = t & 63;
    dst[(size_t)(n0+nn)*K + k0 + kk] = f2bf(tile[kk][nn]);
  }
}

// ---------------- 256x256 8-phase pipelined GEMM (r7 proven) ----------------
__global__ __launch_bounds__(512, 1)
void gemm256p_kernel(const short* __restrict__ A, const short* __restrict__ Bt,
                     short* __restrict__ C, const float* __restrict__ bias,
                     int M, int N, int K)
{
  __shared__ __align__(16) short lds[65536];   // 128 KiB
  char* ldsc = (char*)lds;
  const int t = threadIdx.x, lane = t & 63, wid = t >> 6;
  const int wm = wid >> 2, wn = wid & 3;

  const int nwg = gridDim.x * gridDim.y;
  const int id = blockIdx.y * gridDim.x + blockIdx.x;
  const int work = (id & 7) * (nwg >> 3) + (id >> 3);
  const int bn = work % gridDim.x, bm = work / gridDim.x;
  const int m0 = bm * 256, n0 = bn * 256;

  f32x4 acc[8][4];
#pragma unroll
  for (int m=0;m<8;m++)
#pragma unroll
    for (int n=0;n<4;n++) acc[m][n] = zero_f4();

  const int hK = K << 7;
  const short* pA[2]; const short* pB[2]; int ldst[2];
#pragma unroll
  for (int i = 0; i < 2; i++) {
    int chunk = i*512 + t;
    int rh = chunk >> 3, sl = chunk & 7;
    int ss = sl ^ (rh & 7);
    pA[i] = A + (size_t)(m0 + rh)*K + ss*8;
    pB[i] = Bt + (size_t)(n0 + rh)*K + ss*8;
    ldst[i] = (i*512 + (wid << 6))*16;
  }
  auto stage = [&](int tile, int mat, int half) {
    char* dbase = ldsc + mat*65536 + (tile & 1)*32768 + half*16384;
#pragma unroll
    for (int i = 0; i < 2; i++) {
      const short* src = (mat ? pB[i] : pA[i]) + half*hK + tile*64;
      gload16(src, dbase + ldst[i]);
    }
  };

  const int sk0 = (((lane >> 4)    ) ^ (lane & 7)) * 16;
  const int sk1 = ((4 + (lane >> 4)) ^ (lane & 7)) * 16;
  const int rowb = (lane & 15) * 128;
  const char* aB[2] = { ldsc + wm*16384 + rowb + sk0, ldsc + wm*16384 + rowb + sk1 };
  const char* bB[2] = { ldsc + 65536 + wn*8192 + rowb + sk0, ldsc + 65536 + wn*8192 + rowb + sk1 };

#define PHASE(BUF, Q, STAGE_STMT, GATE) do {                               \
    if ((Q) == 0) {                                                        \
      _Pragma("unroll") for (int n_=0;n_<4;n_++)                           \
        _Pragma("unroll") for (int k_=0;k_<2;k_++)                         \
          bfr[n_][k_] = *(const bf16x8*)(bB[k_] + (BUF)*32768 + n_*2048);  \
    }                                                                      \
    _Pragma("unroll") for (int i_=0;i_<2;i_++)                             \
      _Pragma("unroll") for (int k_=0;k_<2;k_++)                           \
        afr[i_][k_] = *(const bf16x8*)(aB[k_] + (BUF)*32768 + (2*(Q)+i_)*2048); \
    STAGE_STMT;                                                            \
    GATE;                                                                  \
    __builtin_amdgcn_sched_barrier(0);                                     \
    __builtin_amdgcn_s_barrier();                                          \
    asm volatile("s_waitcnt lgkmcnt(0)" ::: "memory");                     \
    __builtin_amdgcn_sched_barrier(0);                                     \
    __builtin_amdgcn_s_setprio(1);                                         \
    _Pragma("unroll") for (int k_=0;k_<2;k_++)                             \
      _Pragma("unroll") for (int i_=0;i_<2;i_++)                           \
        _Pragma("unroll") for (int n_=0;n_<4;n_++)                         \
          acc[2*(Q)+i_][n_] = __builtin_amdgcn_mfma_f32_16x16x32_bf16(     \
              afr[i_][k_], bfr[n_][k_], acc[2*(Q)+i_][n_], 0, 0, 0);       \
    __builtin_amdgcn_s_setprio(0);                                         \
    __builtin_amdgcn_sched_barrier(0);                                     \
    __builtin_amdgcn_s_barrier();                                          \
  } while (0)

  const int NU = K >> 7;
  stage(0, 0, 0); stage(0, 0, 1); stage(0, 1, 0); stage(0, 1, 1);
  stage(1, 1, 0); stage(1, 1, 1);
  WAITV(4);
  __builtin_amdgcn_sched_barrier(0);
  __builtin_amdgcn_s_barrier();

#pragma unroll 1
  for (int u = 0; u < NU; ++u) {
    const int t0 = 2*u, t1 = t0 + 1;
    const bool more = (u + 1 < NU);
    bf16x8 bfr[4][2], afr[2][2];
    PHASE(0, 0, stage(t1, 0, 0),               (void)0);
    PHASE(0, 1, stage(t1, 0, 1),               (void)0);
    PHASE(0, 2, if (more) stage(t0+2, 1, 0),   (void)0);
    PHASE(0, 3, if (more) stage(t0+2, 1, 1),   if (more) { WAITV(4); } else { WAITV(0); });
    PHASE(1, 0, if (more) stage(t0+2, 0, 0),   (void)0);
    PHASE(1, 1, if (more) stage(t0+2, 0, 1),   (void)0);
    PHASE(1, 2, if (more) stage(t1+2, 1, 0),   (void)0);
    PHASE(1, 3, if (more) stage(t1+2, 1, 1),   if (more) { WAITV(4); });
  }
#undef PHASE

  const int g = lane >> 4;
#pragma unroll
  for (int m=0;m<8;m++) {
#pragma unroll
    for (int n=0;n<4;n++) {
#pragma unroll
      for (int r=0;r<4;r++) {
        int mm = m0 + wm*128 + m*16 + g*4 + r;
        int nn = n0 + wn*64 + n*16 + (lane & 15);
        float v = acc[m][n][r] + bias[nn];
        C[(size_t)mm*N + nn] = f2bf(v);
      }
    }
  }
}

// ---------------- 128x128 GEMM (small shapes) ----------------
// EPI: 0 bf16 store, 1 gelu+bf16, 4 f32 partial store (split-K z)
template<int EPI, bool HAS_BIAS>
__global__ __launch_bounds__(256, 2)
void gemm_kernel(const short* __restrict__ A, const short* __restrict__ Bt,
                 void* __restrict__ Cout, const float* __restrict__ bias,
                 int M, int N, int K, int ldk)
{
  __shared__ __align__(16) short As[128*64];
  __shared__ __align__(16) short Bs[128*64];
  const int t = threadIdx.x;
  const int lane = t & 63, w = t >> 6;
  const int m0 = blockIdx.x * 128, n0 = blockIdx.y * 128;
  const int wr = (w >> 1) * 64, wc = (w & 1) * 64;
  const short* Ap = A + (size_t)blockIdx.z * K;
  const short* Btp = Bt + (size_t)blockIdx.z * K;

  f32x4 acc[4][4];
#pragma unroll
  for (int i=0;i<4;i++)
#pragma unroll
    for (int j=0;j<4;j++) acc[i][j] = zero_f4();

  for (int kt = 0; kt < K; kt += 64) {
#pragma unroll
    for (int i = 0; i < 4; i++) {
      int chunk = i*256 + t;
      int row = chunk >> 3, slot = chunk & 7;
      int ss = slot ^ (row & 7);
      gload16(Ap + (size_t)(m0 + row)*ldk + kt + ss*8,
              (char*)As + (i*256 + (w<<6))*16);
    }
#pragma unroll
    for (int i = 0; i < 4; i++) {
      int chunk = i*256 + t;
      int row = chunk >> 3, slot = chunk & 7;
      int ss = slot ^ (row & 7);
      gload16(Btp + (size_t)(n0 + row)*ldk + kt + ss*8,
              (char*)Bs + (i*256 + (w<<6))*16);
    }
    __syncthreads();

#pragma unroll
    for (int ks = 0; ks < 2; ks++) {
      bf16x8 af[4], bfr[4];
#pragma unroll
      for (int i=0;i<4;i++) {
        int row = wr + i*16 + (lane & 15);
        int slot = (ks*4 + (lane >> 4)) ^ (row & 7);
        af[i] = *(const bf16x8*)((const char*)As + row*128 + slot*16);
        int nrow = wc + i*16 + (lane & 15);
        int nslot = (ks*4 + (lane >> 4)) ^ (nrow & 7);
        bfr[i] = *(const bf16x8*)((const char*)Bs + nrow*128 + nslot*16);
      }
#pragma unroll
      for (int i=0;i<4;i++)
#pragma unroll
        for (int j=0;j<4;j++)
          acc[i][j] = __builtin_amdgcn_mfma_f32_16x16x32_bf16(af[i], bfr[j], acc[i][j], 0, 0, 0);
    }
    __syncthreads();
  }

  const int g = lane >> 4;
#pragma unroll
  for (int i=0;i<4;i++) {
#pragma unroll
    for (int j=0;j<4;j++) {
#pragma unroll
      for (int r=0;r<4;r++) {
        int m = m0 + wr + i*16 + g*4 + r;
        int n = n0 + wc + j*16 + (lane & 15);
        float v = acc[i][j][r];
        if (EPI == 0) {
          if (HAS_BIAS) v += bias[n];
          ((short*)Cout)[(size_t)m*N + n] = f2bf(v);
        } else if (EPI == 1) {
          if (HAS_BIAS) v += bias[n];
          float gl = 0.5f * v * (1.0f + erff(v * 0.70710678f));
          ((short*)Cout)[(size_t)m*N + n] = f2bf(gl);
        } else {
          ((float*)Cout)[(size_t)blockIdx.z*M*N + (size_t)m*N + n] = v;
        }
      }
    }
  }
}

// ---------------- Wo reduce (2 partials) + residual + ffln LN -> hbuf ----------------
__global__ __launch_bounds__(256)
void wored_ffln_kernel(const float* __restrict__ part, float* __restrict__ lat,
                       const float* __restrict__ w, const float* __restrict__ bb,
                       short* __restrict__ hbuf)
{
  __shared__ float sh[8];
  int r = blockIdx.x, t = threadIdx.x;
  int idx = r*256 + t;
  float4 a = ((float4*)lat)[idx];
  float4 p0 = ((const float4*)part)[idx];
  float4 p1 = ((const float4*)(part + (size_t)LROWS*DIM))[idx];
  a.x += p0.x + p1.x; a.y += p0.y + p1.y; a.z += p0.z + p1.z; a.w += p0.w + p1.w;
  ((float4*)lat)[idx] = a;
  float s = a.x+a.y+a.z+a.w;
  float sq = a.x*a.x+a.y*a.y+a.z*a.z+a.w*a.w;
  reduce2(s, sq, sh);
  float mean = s*(1.0f/DIM), var = sq*(1.0f/DIM) - mean*mean;
  float rs = rsqrtf(var + 1e-5f);
  float4 wv = ((const float4*)w)[t], bv = ((const float4*)bb)[t];
  short4 o;
  o.x = f2bf((a.x-mean)*rs*wv.x + bv.x);
  o.y = f2bf((a.y-mean)*rs*wv.y + bv.y);
  o.z = f2bf((a.z-mean)*rs*wv.z + bv.z);
  o.w = f2bf((a.w-mean)*rs*wv.w + bv.w);
  ((short4*)(hbuf + (size_t)r*DIM))[t] = o;
}

// ---------------- W2 split-K reduce + residual + LN(next lnl or final fln) ----------------
template<bool LAST>
__global__ __launch_bounds__(256)
void w2red_ln_kernel(const float* __restrict__ part, const float* __restrict__ b2,
                     float* __restrict__ lat, const float* __restrict__ w,
                     const float* __restrict__ bb, void* __restrict__ dst)
{
  __shared__ float sh[8];
  int r = blockIdx.x, t = threadIdx.x;
  int idx = r*256 + t;
  float4 a = ((float4*)lat)[idx];
  float4 b4 = ((const float4*)b2)[t];
  a.x += b4.x; a.y += b4.y; a.z += b4.z; a.w += b4.w;
#pragma unroll
  for (int z = 0; z < 4; z++) {
    float4 p = ((const float4*)(part + (size_t)z*LROWS*DIM))[idx];
    a.x += p.x; a.y += p.y; a.z += p.z; a.w += p.w;
  }
  ((float4*)lat)[idx] = a;
  float s = a.x+a.y+a.z+a.w;
  float sq = a.x*a.x+a.y*a.y+a.z*a.z+a.w*a.w;
  reduce2(s, sq, sh);
  float mean = s*(1.0f/DIM), var = sq*(1.0f/DIM) - mean*mean;
  float rs = rsqrtf(var + 1e-5f);
  float4 wv = ((const float4*)w)[t], bv = ((const float4*)bb)[t];
  float o0 = (a.x-mean)*rs*wv.x + bv.x;
  float o1 = (a.y-mean)*rs*wv.y + bv.y;
  float o2 = (a.z-mean)*rs*wv.z + bv.z;
  float o3 = (a.w-mean)*rs*wv.w + bv.w;
  if (LAST) {
    float4 o; o.x=o0; o.y=o1; o.z=o2; o.w=o3;
    ((float4*)((float*)dst + (size_t)r*DIM))[t] = o;
  } else {
    short4 o; o.x=f2bf(o0); o.y=f2bf(o1); o.z=f2bf(o2); o.w=f2bf(o3);
    ((short4*)((short*)dst + (size_t)r*DIM))[t] = o;
  }
}

// ---------------- attention pass 1: 4-way split-K flash, register softmax ----------------
// grid 512 = (bt*8+h)*4 + s. Splits 0..2: 8 chunks of 128 keys; split 3: 8 + latent 64.
__global__ __launch_bounds__(256, 2)
void attn_part_kernel(const short* __restrict__ qkvlat, const short* __restrict__ kvbuf,
                      float* __restrict__ part_O, float* __restrict__ part_m,
                      float* __restrict__ part_l)
{
  __shared__ __align__(16) short q_sh[64*64];
  __shared__ __align__(16) short K_sh[128*64];
  __shared__ __align__(16) short VT_sh[64*128];
  __shared__ __align__(16) short P_sh[64*132];

  const int t = threadIdx.x, lane = t & 63, w = t >> 6;
  const int bid = blockIdx.x;
  const int s = bid & 3, bh = bid >> 2;
  const int h = bh & 7, bt = bh >> 3;

  {
    const short* qsrc = qkvlat + (size_t)(bt*64)*QKVN + h*64;
#pragma unroll
    for (int i = 0; i < 2; i++) {
      int chunk = i*256 + t;
      int row = chunk >> 3, slot = chunk & 7;
      gload16(qsrc + (size_t)row*QKVN + ((slot ^ (row & 7))*8),
              (char*)q_sh + (i*256 + (w<<6))*16);
    }
  }

  float m_run[4], l_run[4];
#pragma unroll
  for (int r=0;r<4;r++){ m_run[r] = -1e30f; l_run[r] = 0.f; }
  f32x4 oacc[4];
#pragma unroll
  for (int j=0;j<4;j++) oacc[j] = zero_f4();

  const int nch = (s == 3) ? 9 : 8;
  for (int c5 = 0; c5 < nch; c5++) {
    __syncthreads();
    const bool isLat = (c5 == 8);
    const int jv = isLat ? 4 : 8;
    const short* kbase; int kstride, valid;
    if (!isLat) {
      kbase = kvbuf + ((size_t)bt*4096 + (s*8 + c5)*128)*DIM + h*64;
      kstride = DIM; valid = 128;
    } else {
      kbase = qkvlat + (size_t)(bt*64)*QKVN + 512 + h*64;
      kstride = QKVN; valid = 64;
    }
    const short* vbase = kbase + 512;

#pragma unroll
    for (int i = 0; i < 4; i++) {
      int chunk = i*256 + t;
      int row = chunk >> 3, slot = chunk & 7;
      gload16(kbase + (size_t)row*kstride + ((slot ^ (row & 7))*8),
              (char*)K_sh + (i*256 + (w<<6))*16);
    }
    // V^T staging: rotate-by-(dh&0x78) layout -> write conflicts 2-way (vs 16-way XOR)
#pragma unroll
    for (int i = 0; i < 4; i++) {
      int c = i*256 + t;
      int row = c >> 3, slot = c & 7;
      bf16x8 v = (row < valid) ? *(const bf16x8*)(vbase + (size_t)row*kstride + slot*8) : zero_b8();
#pragma unroll
      for (int e=0;e<8;e++) {
        int dh = slot*8 + e;
        VT_sh[dh*128 + ((row + (dh & 0x78)) & 127)] = v[e];
      }
    }
    __syncthreads();

    f32x4 sacc[8];
#pragma unroll
    for (int j=0;j<8;j++) sacc[j] = zero_f4();
#pragma unroll
    for (int ks=0; ks<2; ks++) {
      int arow = w*16 + (lane & 15);
      int aslot = (ks*4 + (lane >> 4)) ^ (arow & 7);
      bf16x8 af = *(const bf16x8*)((const char*)q_sh + arow*128 + aslot*16);
#pragma unroll
      for (int j=0;j<8;j++) {
        int brow = j*16 + (lane & 15);
        int bslot = (ks*4 + (lane >> 4)) ^ (brow & 7);
        bf16x8 bv = *(const bf16x8*)((const char*)K_sh + brow*128 + bslot*16);
        sacc[j] = __builtin_amdgcn_mfma_f32_16x16x32_bf16(af, bv, sacc[j], 0, 0, 0);
      }
    }

    float mx[4];
#pragma unroll
    for (int r=0;r<4;r++) mx[r] = -1e30f;
#pragma unroll
    for (int j=0;j<8;j++) {
      if (j < jv) {
#pragma unroll
        for (int r=0;r<4;r++) mx[r] = fmaxf(mx[r], sacc[j][r]);
      }
    }
#pragma unroll
    for (int m2=1; m2<16; m2<<=1) {
#pragma unroll
      for (int r=0;r<4;r++) mx[r] = fmaxf(mx[r], __shfl_xor(mx[r], m2, 64));
    }
    float alpha[4], rowsum[4];
#pragma unroll
    for (int r=0;r<4;r++) {
      float nm = fmaxf(m_run[r], mx[r]);
      alpha[r] = __expf(m_run[r] - nm);
      m_run[r] = nm;
      rowsum[r] = 0.f;
    }
#pragma unroll
    for (int j=0;j<8;j++) {
#pragma unroll
      for (int r=0;r<4;r++) {
        float p = 0.f;
        if (j < jv) { p = __expf(sacc[j][r] - m_run[r]); rowsum[r] += p; }
        P_sh[(w*16 + (lane>>4)*4 + r)*132 + j*16 + (lane & 15)] = f2bf(p);
      }
    }
#pragma unroll
    for (int m2=1; m2<16; m2<<=1) {
#pragma unroll
      for (int r=0;r<4;r++) rowsum[r] += __shfl_xor(rowsum[r], m2, 64);
    }
#pragma unroll
    for (int r=0;r<4;r++) l_run[r] = l_run[r]*alpha[r] + rowsum[r];
#pragma unroll
    for (int j=0;j<4;j++) {
#pragma unroll
      for (int r=0;r<4;r++) oacc[j][r] *= alpha[r];
    }
    __syncthreads();

#pragma unroll
    for (int ks=0; ks<4; ks++) {
      int prow = w*16 + (lane & 15);
      bf16x8 af = *(const bf16x8*)((const char*)P_sh + prow*264 + ks*64 + (lane >> 4)*16);
#pragma unroll
      for (int j=0;j<4;j++) {
        int dh = j*16 + (lane & 15);
        int kb = (ks*4 + (lane >> 4))*8;
        const short* vp = VT_sh + dh*128 + ((kb + (dh & 0x78)) & 127);
        bf16x8 bv = *(const bf16x8*)vp;
        oacc[j] = __builtin_amdgcn_mfma_f32_16x16x32_bf16(af, bv, oacc[j], 0, 0, 0);
      }
    }
  }

  {
    float* Ob = part_O + (size_t)bid*4096;
    int rbase = w*16 + (lane>>4)*4;
#pragma unroll
    for (int j=0;j<4;j++) {
#pragma unroll
      for (int r=0;r<4;r++)
        Ob[(rbase + r)*64 + j*16 + (lane & 15)] = oacc[j][r];
    }
    if ((lane & 15) == 0) {
#pragma unroll
      for (int r=0;r<4;r++) {
        part_m[(size_t)bid*64 + rbase + r] = m_run[r];
        part_l[(size_t)bid*64 + rbase + r] = l_run[r];
      }
    }
  }
}

// ---------------- attention pass 2: combine 4 splits ----------------
__global__ __launch_bounds__(256)
void attn_combine_kernel(const float* __restrict__ part_O, const float* __restrict__ part_m,
                         const float* __restrict__ part_l, short* __restrict__ obuf)
{
  int bh = blockIdx.x, t = threadIdx.x;
  int q = t >> 2, c0 = (t & 3) * 16;
  int bt = bh >> 3, h = bh & 7;
  float m4[4], w4[4];
  float mmax = -1e30f;
#pragma unroll
  for (int s=0;s<4;s++) { m4[s] = part_m[(size_t)(bh*4+s)*64 + q]; mmax = fmaxf(mmax, m4[s]); }
  float lt = 0.f;
#pragma unroll
  for (int s=0;s<4;s++) { w4[s] = __expf(m4[s] - mmax); lt += w4[s] * part_l[(size_t)(bh*4+s)*64 + q]; }
  float inv = 1.0f / lt;
  float4 acc[4];
#pragma unroll
  for (int u=0;u<4;u++) { acc[u].x=0.f; acc[u].y=0.f; acc[u].z=0.f; acc[u].w=0.f; }
#pragma unroll
  for (int s=0;s<4;s++) {
    const float4* Ob = (const float4*)(part_O + ((size_t)(bh*4+s)*64 + q)*64 + c0);
#pragma unroll
    for (int u=0;u<4;u++) {
      float4 v = Ob[u];
      acc[u].x += w4[s]*v.x; acc[u].y += w4[s]*v.y;
      acc[u].z += w4[s]*v.z; acc[u].w += w4[s]*v.w;
    }
  }
  short* ob = obuf + (size_t)(bt*64 + q)*INNER + h*64 + c0;
#pragma unroll
  for (int u=0;u<4;u++) {
    short4 o;
    o.x = f2bf(acc[u].x*inv); o.y = f2bf(acc[u].y*inv);
    o.z = f2bf(acc[u].z*inv); o.w = f2bf(acc[u].w*inv);
    ((short4*)ob)[u] = o;
  }
}

// ---------------- launch ----------------
extern "C" void kernel_launch(void* const* d_in, const int* in_sizes, int n_in,
                              void* d_out, int out_size, void* d_ws, size_t ws_size,
                              hipStream_t stream)
{
  (void)in_sizes; (void)n_in; (void)out_size; (void)ws_size;
  const float* x        = (const float*)d_in[0];
  const float* latents  = (const float*)d_in[1];
  const float* frame_e  = (const float*)d_in[2];
  const float* media_e  = (const float*)d_in[3];
  const float* lnm_w    = (const float*)d_in[4];
  const float* lnm_b    = (const float*)d_in[5];
  const float* lnl_w    = (const float*)d_in[6];
  const float* lnl_b    = (const float*)d_in[7];
  const float* Wq       = (const float*)d_in[8];
  const float* Wkv      = (const float*)d_in[9];
  const float* Wo       = (const float*)d_in[10];
  const float* ffln_w   = (const float*)d_in[11];
  const float* ffln_b   = (const float*)d_in[12];
  const float* W1       = (const float*)d_in[13];
  const float* b1       = (const float*)d_in[14];
  const float* W2       = (const float*)d_in[15];
  const float* b2       = (const float*)d_in[16];
  const float* fln_w    = (const float*)d_in[17];
  const float* fln_b    = (const float*)d_in[18];
  float* out = (float*)d_out;

  char* ws = (char*)d_ws;
  size_t off = 0;
  short* xhat   = (short*)(ws + off); off += (size_t)XROWS*DIM*2;
  short* kvbuf  = (short*)(ws + off); off += (size_t)XROWS*DIM*2;
  short* Wkvf_a = (short*)(ws + off); off += (size_t)DEPTH*DIM*DIM*2;
  short* qkvW_a = (short*)(ws + off); off += (size_t)DEPTH*QKVN*DIM*2;
  short* Wo_a   = (short*)(ws + off); off += (size_t)DEPTH*INNER*DIM*2;
  short* W1_a   = (short*)(ws + off); off += (size_t)DEPTH*DIM*FFD*2;
  short* W2_a   = (short*)(ws + off); off += (size_t)DEPTH*FFD*DIM*2;
  float* kvb    = (float*)(ws + off); off += (size_t)DEPTH*DIM*4;
  float* kvbp   = (float*)(ws + off); off += (size_t)DEPTH*16*DIM*4;
  float* lat    = (float*)(ws + off); off += (size_t)LROWS*DIM*4;
  short* lnlat  = (short*)(ws + off); off += (size_t)LROWS*DIM*2;
  short* qkvlat = (short*)(ws + off); off += (size_t)LROWS*QKVN*2;
  short* obuf   = (short*)(ws + off); off += (size_t)LROWS*INNER*2;
  short* hbuf   = (short*)(ws + off); off += (size_t)LROWS*DIM*2;
  short* h1     = (short*)(ws + off); off += (size_t)LROWS*FFD*2;
  float* wopart = (float*)(ws + off); off += (size_t)2*LROWS*DIM*4;
  // part_O (attn, 8MB) and w2part (ffn, 16MB) live at disjoint times: share (16MB)
  float* part_O = (float*)(ws + off); off += (size_t)4*LROWS*DIM*4;
  float* w2part = part_O;
  float* part_m = (float*)(ws + off); off += (size_t)512*64*4;
  float* part_l = (float*)(ws + off); off += (size_t)512*64*4;

  prep_kernel<<<XROWS/4, 256, 0, stream>>>(x, frame_e, media_e, xhat);
  latinit_ln_kernel<<<LROWS, 256, 0, stream>>>(latents, lnl_w, lnl_b, lat, lnlat);
  kvbp_kernel<<<dim3(16, DEPTH), 256, 0, stream>>>(lnm_b, Wkv, kvbp);
  kvbred_kernel<<<DEPTH, 256, 0, stream>>>(kvbp, kvb);
  tcast_all6_kernel<<<DEPTH*2816, 256, 0, stream>>>(
      Wkv, Wq, Wo, W1, W2, lnm_w, Wkvf_a, qkvW_a, Wo_a, W1_a, W2_a);

  for (int i = 0; i < DEPTH; i++) {
    const short* Wkv_f = Wkvf_a + (size_t)i*DIM*DIM;
    const short* qkvW  = qkvW_a + (size_t)i*QKVN*DIM;
    const short* Wo_h  = Wo_a   + (size_t)i*INNER*DIM;
    const short* W1_h  = W1_a   + (size_t)i*DIM*FFD;
    const short* W2_h  = W2_a   + (size_t)i*FFD*DIM;

    gemm_kernel<0,false><<<dim3(LROWS/128, QKVN/128), 256, 0, stream>>>(
        lnlat, qkvW, qkvlat, nullptr, LROWS, QKVN, DIM, DIM);
    gemm256p_kernel<<<dim3(DIM/256, XROWS/256), 512, 0, stream>>>(
        xhat, Wkv_f, kvbuf, kvb + i*DIM, XROWS, DIM, DIM);
    attn_part_kernel<<<512, 256, 0, stream>>>(qkvlat, kvbuf, part_O, part_m, part_l);
    attn_combine_kernel<<<128, 256, 0, stream>>>(part_O, part_m, part_l, obuf);
    gemm_kernel<4,false><<<dim3(LROWS/128, DIM/128, 2), 256, 0, stream>>>(
        obuf, Wo_h, wopart, nullptr, LROWS, DIM, 256, INNER);
    wored_ffln_kernel<<<LROWS, 256, 0, stream>>>(
        wopart, lat, ffln_w + i*DIM, ffln_b + i*DIM, hbuf);
    gemm_kernel<1,true><<<dim3(LROWS/128, FFD/128), 256, 0, stream>>>(
        hbuf, W1_h, h1, b1 + (size_t)i*FFD, LROWS, FFD, DIM, DIM);
    gemm_kernel<4,false><<<dim3(LROWS/128, DIM/128, 4), 256, 0, stream>>>(
        h1, W2_h, w2part, nullptr, LROWS, DIM, DIM, FFD);
    if (i < DEPTH-1)
      w2red_ln_kernel<false><<<LROWS, 256, 0, stream>>>(
          w2part, b2 + (size_t)i*DIM, lat, lnl_w + (i+1)*DIM, lnl_b + (i+1)*DIM, lnlat);
    else
      w2red_ln_kernel<true><<<LROWS, 256, 0, stream>>>(
          w2part, b2 + (size_t)i*DIM, lat, fln_w, fln_b, out);
  }
}

// Round 13
// 1892.016 us; speedup vs baseline: 1.1586x; 1.0176x over previous
//
#include <hip/hip_runtime.h>
#include <math.h>

// PerceiverResampler on MI355X.
// xhat = rownorm(x + frame_emb + media_emb) once (bf16); per-layer LN affine folded
// into Wkv; all per-layer weights transpose-cast once upfront.
// Upfront work (prep/latinit/tcast6/kvbp) merged into ONE dispatch (independent paths).
// Per layer: mega1 = r7-proven 8-phase 256x256 kv-GEMM (blocks 0-1023) + qkv rider
// (blocks 1024-1119, r6-verified path). Wo split-K4. Fused reduce+LN kernels.

#define DIM   1024
#define DEPTH 6
#define HEADS 8
#define NLAT  64
#define INNER 512
#define FFD   4096
#define XROWS 65536
#define LROWS 1024
#define NBT   16
#define QKVN  1536

typedef __attribute__((ext_vector_type(8))) short bf16x8;
typedef __attribute__((ext_vector_type(4))) float f32x4;

#define WAITV(n) asm volatile("s_waitcnt vmcnt(" #n ")" ::: "memory")

__device__ __forceinline__ short f2bf(float f) {
  union { float f; unsigned u; } v; v.f = f;
  unsigned r = v.u + 0x7fffu + ((v.u >> 16) & 1u);
  return (short)(r >> 16);
}

__device__ __forceinline__ void gload16(const void* g, void* l) {
  __builtin_amdgcn_global_load_lds(
      (const __attribute__((address_space(1))) unsigned int*)g,
      (__attribute__((address_space(3))) unsigned int*)l, 16, 0, 0);
}

__device__ __forceinline__ f32x4 zero_f4() { f32x4 z; z[0]=0.f; z[1]=0.f; z[2]=0.f; z[3]=0.f; return z; }
__device__ __forceinline__ bf16x8 zero_b8() { bf16x8 z;
#pragma unroll
  for (int e=0;e<8;e++) z[e]=0; return z; }

__device__ __forceinline__ void reduce2s(float& s, float& sq, float* sh) {
#pragma unroll
  for (int off = 32; off >= 1; off >>= 1) {
    s  += __shfl_xor(s,  off, 64);
    sq += __shfl_xor(sq, off, 64);
  }
  int t = threadIdx.x;
  if ((t & 63) == 0) { sh[(t >> 6)*2] = s; sh[(t >> 6)*2 + 1] = sq; }
  __syncthreads();
  s  = sh[0] + sh[2] + sh[4] + sh[6];
  sq = sh[1] + sh[3] + sh[5] + sh[7];
}

// ================= upfront mega: prep | latinit_ln | tcast6 | kvbp =================
__global__ __launch_bounds__(256)
void mega0_kernel(const float* __restrict__ x, const float* __restrict__ fe,
                  const float* __restrict__ me, short* __restrict__ xhat,
                  const float* __restrict__ latents, const float* __restrict__ lnl_w,
                  const float* __restrict__ lnl_b, float* __restrict__ lat,
                  short* __restrict__ lnlat,
                  const float* __restrict__ Wkv, const float* __restrict__ Wq,
                  const float* __restrict__ Wo, const float* __restrict__ W1,
                  const float* __restrict__ W2, const float* __restrict__ lnm_w,
                  short* __restrict__ Wkvf_a, short* __restrict__ qkvW_a,
                  short* __restrict__ Wo_a, short* __restrict__ W1_a,
                  short* __restrict__ W2_a,
                  const float* __restrict__ lnm_b, float* __restrict__ kvb_part)
{
  __shared__ float smem[64*65];
  const int blk = blockIdx.x, t = threadIdx.x;

  if (blk < 16384) {
    // ---- prep: xhat = rownorm(x + fe[f] + me[tt]); one wave per row ----
    int lane = t & 63;
    int r = blk*4 + (t >> 6);
    int f = (r >> 8) & 15, tt = (r >> 12) & 7;
    const float4* xp = (const float4*)(x + (size_t)r*DIM);
    const float4* fp = (const float4*)(fe + (size_t)f*DIM);
    const float4* mp = (const float4*)(me + (size_t)tt*DIM);
    float y[16];
    float s = 0.f, sq = 0.f;
#pragma unroll
    for (int k = 0; k < 4; k++) {
      float4 xv = xp[k*64 + lane], fv = fp[k*64 + lane], mv = mp[k*64 + lane];
      float a0 = xv.x+fv.x+mv.x, a1 = xv.y+fv.y+mv.y, a2 = xv.z+fv.z+mv.z, a3 = xv.w+fv.w+mv.w;
      y[k*4+0]=a0; y[k*4+1]=a1; y[k*4+2]=a2; y[k*4+3]=a3;
      s += a0+a1+a2+a3; sq += a0*a0+a1*a1+a2*a2+a3*a3;
    }
#pragma unroll
    for (int off = 32; off >= 1; off >>= 1) {
      s  += __shfl_xor(s,  off, 64);
      sq += __shfl_xor(sq, off, 64);
    }
    float mean = s * (1.0f/DIM);
    float var  = sq * (1.0f/DIM) - mean*mean;
    float rs = rsqrtf(var + 1e-5f);
    short4* op = (short4*)(xhat + (size_t)r*DIM);
#pragma unroll
    for (int k = 0; k < 4; k++) {
      short4 o;
      o.x = f2bf((y[k*4+0]-mean)*rs); o.y = f2bf((y[k*4+1]-mean)*rs);
      o.z = f2bf((y[k*4+2]-mean)*rs); o.w = f2bf((y[k*4+3]-mean)*rs);
      op[k*64 + lane] = o;
    }
  } else if (blk < 17408) {
    // ---- latinit + LN(layer0 lnl); one row per block ----
    int r = blk - 16384;
    int i = r & 63;
    float4 a = ((const float4*)(latents + (size_t)i*DIM))[t];
    ((float4*)(lat + (size_t)r*DIM))[t] = a;
    float s = a.x+a.y+a.z+a.w;
    float sq = a.x*a.x+a.y*a.y+a.z*a.z+a.w*a.w;
    reduce2s(s, sq, smem);
    float mean = s*(1.0f/DIM), var = sq*(1.0f/DIM) - mean*mean;
    float rs = rsqrtf(var + 1e-5f);
    float4 wv = ((const float4*)lnl_w)[t], bv = ((const float4*)lnl_b)[t];
    short4 o;
    o.x = f2bf((a.x-mean)*rs*wv.x + bv.x);
    o.y = f2bf((a.y-mean)*rs*wv.y + bv.y);
    o.z = f2bf((a.z-mean)*rs*wv.z + bv.z);
    o.w = f2bf((a.w-mean)*rs*wv.w + bv.w);
    ((short4*)(lnlat + (size_t)r*DIM))[t] = o;
  } else if (blk < 34304) {
    // ---- tcast6: all-layer weight transpose-cast ----
    int bb = blk - 17408;
    int L = bb / 2816;
    int b = bb % 2816;
    const float* lWkv = Wkv + (size_t)L*DIM*DIM;
    const float* src; short* dst; const float* fold = nullptr; float scale = 1.0f;
    int K, N, bx, ntx;
    if (b < 256)      { src=lWkv; dst=Wkvf_a + (size_t)L*DIM*DIM; fold=lnm_w + (size_t)L*DIM; K=1024; N=1024; bx=b; ntx=16; }
    else if (b < 384) { src=Wq + (size_t)L*DIM*INNER; dst=qkvW_a + (size_t)L*QKVN*DIM; scale=0.125f; K=1024; N=512; bx=b-256; ntx=8; }
    else if (b < 640) { src=lWkv; dst=qkvW_a + (size_t)L*QKVN*DIM + (size_t)512*1024; K=1024; N=1024; bx=b-384; ntx=16; }
    else if (b < 768) { src=Wo + (size_t)L*INNER*DIM; dst=Wo_a + (size_t)L*INNER*DIM; K=512;  N=1024; bx=b-640; ntx=16; }
    else if (b < 1792){ src=W1 + (size_t)L*DIM*FFD; dst=W1_a + (size_t)L*DIM*FFD; K=1024; N=4096; bx=b-768; ntx=64; }
    else              { src=W2 + (size_t)L*FFD*DIM; dst=W2_a + (size_t)L*FFD*DIM; K=4096; N=1024; bx=b-1792; ntx=16; }
    int n0 = (bx % ntx)*64, k0 = (bx / ntx)*64;
#pragma unroll
    for (int i = 0; i < 16; i++) {
      int rr = (t >> 6) + i*4, cc = t & 63;
      float v = src[(size_t)(k0+rr)*N + n0 + cc] * scale;
      if (fold) v *= fold[k0 + rr];
      smem[rr*65 + cc] = v;
    }
    __syncthreads();
#pragma unroll
    for (int i = 0; i < 16; i++) {
      int nn = (t >> 6) + i*4, kk = t & 63;
      dst[(size_t)(n0+nn)*K + k0 + kk] = f2bf(smem[kk*65 + nn]);
    }
  } else {
    // ---- kvbp: split-K partials of lnm_b @ Wkv ----
    int b2 = blk - 34304;
    int z = b2 & 15, i = b2 >> 4;
    const float* W = Wkv + (size_t)i*DIM*DIM;
    const float* bv = lnm_b + (size_t)i*DIM;
    float acc0=0,acc1=0,acc2=0,acc3=0;
    for (int k = z*64; k < z*64+64; k++) {
      float b3 = bv[k];
      const float* Wr = W + (size_t)k*DIM;
      acc0 += b3 * Wr[t];       acc1 += b3 * Wr[t+256];
      acc2 += b3 * Wr[t+512];   acc3 += b3 * Wr[t+768];
    }
    float* o = kvb_part + (size_t)(i*16 + z)*DIM;
    o[t] = acc0; o[t+256] = acc1; o[t+512] = acc2; o[t+768] = acc3;
  }
}

__global__ __launch_bounds__(256)
void kvbred_kernel(const float* __restrict__ kvb_part, float* __restrict__ kvb)
{
  int i = blockIdx.x, t = threadIdx.x;
#pragma unroll
  for (int j = 0; j < 4; j++) {
    int col = t + j*256;
    float s = 0.f;
#pragma unroll
    for (int z = 0; z < 16; z++) s += kvb_part[(size_t)(i*16 + z)*DIM + col];
    kvb[i*DIM + col] = s;
  }
}

// ================= per-layer mega: kv 8-phase GEMM + qkv rider =================

// kv path: r7-proven 256x256 8-phase pipeline. M=XROWS, N=K=DIM. b in [0,1024).
__device__ __forceinline__ void kv256_path(
    const short* __restrict__ A, const short* __restrict__ Bt,
    short* __restrict__ C, const float* __restrict__ bias, int id, char* ldsc)
{
  const int t = threadIdx.x, lane = t & 63, wid = t >> 6;
  const int wm = wid >> 2, wn = wid & 3;
  const int K = DIM, N = DIM;

  const int work = (id & 7) * 128 + (id >> 3);   // XCD-bijective over 1024
  const int bn = work & 3, bm = work >> 2;
  const int m0 = bm * 256, n0 = bn * 256;

  f32x4 acc[8][4];
#pragma unroll
  for (int m=0;m<8;m++)
#pragma unroll
    for (int n=0;n<4;n++) acc[m][n] = zero_f4();

  const int hK = K << 7;
  const short* pA[2]; const short* pB[2]; int ldst[2];
#pragma unroll
  for (int i = 0; i < 2; i++) {
    int chunk = i*512 + t;
    int rh = chunk >> 3, sl = chunk & 7;
    int ss = sl ^ (rh & 7);
    pA[i] = A + (size_t)(m0 + rh)*K + ss*8;
    pB[i] = Bt + (size_t)(n0 + rh)*K + ss*8;
    ldst[i] = (i*512 + (wid << 6))*16;
  }
  auto stage = [&](int tile, int mat, int half) {
    char* dbase = ldsc + mat*65536 + (tile & 1)*32768 + half*16384;
#pragma unroll
    for (int i = 0; i < 2; i++) {
      const short* src = (mat ? pB[i] : pA[i]) + half*hK + tile*64;
      gload16(src, dbase + ldst[i]);
    }
  };

  const int sk0 = (((lane >> 4)    ) ^ (lane & 7)) * 16;
  const int sk1 = ((4 + (lane >> 4)) ^ (lane & 7)) * 16;
  const int rowb = (lane & 15) * 128;
  const char* aB[2] = { ldsc + wm*16384 + rowb + sk0, ldsc + wm*16384 + rowb + sk1 };
  const char* bB[2] = { ldsc + 65536 + wn*8192 + rowb + sk0, ldsc + 65536 + wn*8192 + rowb + sk1 };

#define PHASE(BUF, Q, STAGE_STMT, GATE) do {                               \
    if ((Q) == 0) {                                                        \
      _Pragma("unroll") for (int n_=0;n_<4;n_++)                           \
        _Pragma("unroll") for (int k_=0;k_<2;k_++)                         \
          bfr[n_][k_] = *(const bf16x8*)(bB[k_] + (BUF)*32768 + n_*2048);  \
    }                                                                      \
    _Pragma("unroll") for (int i_=0;i_<2;i_++)                             \
      _Pragma("unroll") for (int k_=0;k_<2;k_++)                           \
        afr[i_][k_] = *(const bf16x8*)(aB[k_] + (BUF)*32768 + (2*(Q)+i_)*2048); \
    STAGE_STMT;                                                            \
    GATE;                                                                  \
    __builtin_amdgcn_sched_barrier(0);                                     \
    __builtin_amdgcn_s_barrier();                                          \
    asm volatile("s_waitcnt lgkmcnt(0)" ::: "memory");                     \
    __builtin_amdgcn_sched_barrier(0);                                     \
    __builtin_amdgcn_s_setprio(1);                                         \
    _Pragma("unroll") for (int k_=0;k_<2;k_++)                             \
      _Pragma("unroll") for (int i_=0;i_<2;i_++)                           \
        _Pragma("unroll") for (int n_=0;n_<4;n_++)                         \
          acc[2*(Q)+i_][n_] = __builtin_amdgcn_mfma_f32_16x16x32_bf16(     \
              afr[i_][k_], bfr[n_][k_], acc[2*(Q)+i_][n_], 0, 0, 0);       \
    __builtin_amdgcn_s_setprio(0);                                         \
    __builtin_amdgcn_sched_barrier(0);                                     \
    __builtin_amdgcn_s_barrier();                                          \
  } while (0)

  const int NU = K >> 7;
  stage(0, 0, 0); stage(0, 0, 1); stage(0, 1, 0); stage(0, 1, 1);
  stage(1, 1, 0); stage(1, 1, 1);
  WAITV(4);
  __builtin_amdgcn_sched_barrier(0);
  __builtin_amdgcn_s_barrier();

#pragma unroll 1
  for (int u = 0; u < NU; ++u) {
    const int t0 = 2*u, t1 = t0 + 1;
    const bool more = (u + 1 < NU);
    bf16x8 bfr[4][2], afr[2][2];
    PHASE(0, 0, stage(t1, 0, 0),               (void)0);
    PHASE(0, 1, stage(t1, 0, 1),               (void)0);
    PHASE(0, 2, if (more) stage(t0+2, 1, 0),   (void)0);
    PHASE(0, 3, if (more) stage(t0+2, 1, 1),   if (more) { WAITV(4); } else { WAITV(0); });
    PHASE(1, 0, if (more) stage(t0+2, 0, 0),   (void)0);
    PHASE(1, 1, if (more) stage(t0+2, 0, 1),   (void)0);
    PHASE(1, 2, if (more) stage(t1+2, 1, 0),   (void)0);
    PHASE(1, 3, if (more) stage(t1+2, 1, 1),   if (more) { WAITV(4); });
  }
#undef PHASE

  const int g = lane >> 4;
#pragma unroll
  for (int m=0;m<8;m++) {
#pragma unroll
    for (int n=0;n<4;n++) {
#pragma unroll
      for (int r=0;r<4;r++) {
        int mm = m0 + wm*128 + m*16 + g*4 + r;
        int nn = n0 + wn*64 + n*16 + (lane & 15);
        float v = acc[m][n][r] + bias[nn];
        C[(size_t)mm*N + nn] = f2bf(v);
      }
    }
  }
}

// qkv rider: 128x128 tile, 8 waves (2M x 4N, per-wave 64x32), BK=64 (r6-verified).
__device__ __forceinline__ void qkv_path(
    const short* __restrict__ A, const short* __restrict__ Bt,
    short* __restrict__ C, int q, char* ldsc)
{
  const int t = threadIdx.x, lane = t & 63, wid = t >> 6;
  const int m0 = (q & 7) * 128, n0 = (q >> 3) * 128;
  const int wr = (wid >> 2) * 64, wc = (wid & 3) * 32;
  char* As = ldsc;
  char* Bs = ldsc + 16384;

  f32x4 acc[4][2];
#pragma unroll
  for (int i=0;i<4;i++)
#pragma unroll
    for (int j=0;j<2;j++) acc[i][j] = zero_f4();

  for (int kt = 0; kt < DIM; kt += 64) {
#pragma unroll
    for (int i = 0; i < 2; i++) {
      int chunk = i*512 + t;
      int row = chunk >> 3, slot = chunk & 7;
      int ss = slot ^ (row & 7);
      gload16(A + (size_t)(m0 + row)*DIM + kt + ss*8, As + (i*512 + (wid<<6))*16);
    }
#pragma unroll
    for (int i = 0; i < 2; i++) {
      int chunk = i*512 + t;
      int row = chunk >> 3, slot = chunk & 7;
      int ss = slot ^ (row & 7);
      gload16(Bt + (size_t)(n0 + row)*DIM + kt + ss*8, Bs + (i*512 + (wid<<6))*16);
    }
    __syncthreads();
#pragma unroll
    for (int ks = 0; ks < 2; ks++) {
      bf16x8 af[4], bfr[2];
#pragma unroll
      for (int i=0;i<4;i++) {
        int row = wr + i*16 + (lane & 15);
        int slot = (ks*4 + (lane >> 4)) ^ (row & 7);
        af[i] = *(const bf16x8*)(As + row*128 + slot*16);
      }
#pragma unroll
      for (int j=0;j<2;j++) {
        int row = wc + j*16 + (lane & 15);
        int slot = (ks*4 + (lane >> 4)) ^ (row & 7);
        bfr[j] = *(const bf16x8*)(Bs + row*128 + slot*16);
      }
#pragma unroll
      for (int i=0;i<4;i++)
#pragma unroll
        for (int j=0;j<2;j++)
          acc[i][j] = __builtin_amdgcn_mfma_f32_16x16x32_bf16(af[i], bfr[j], acc[i][j], 0, 0, 0);
    }
    __syncthreads();
  }

  const int g = lane >> 4;
#pragma unroll
  for (int i=0;i<4;i++) {
#pragma unroll
    for (int j=0;j<2;j++) {
#pragma unroll
      for (int r=0;r<4;r++) {
        int mm = m0 + wr + i*16 + g*4 + r;
        int nn = n0 + wc + j*16 + (lane & 15);
        C[(size_t)mm*QKVN + nn] = f2bf(acc[i][j][r]);
      }
    }
  }
}

// mega1: [0,1024) kv | [1024,1120) qkv rider
__global__ __launch_bounds__(512, 1)
void mega1_kernel(const short* __restrict__ xhat, const short* __restrict__ Wkvf,
                  const float* __restrict__ kvb_i, short* __restrict__ kvbuf,
                  const short* __restrict__ lnlat, const short* __restrict__ qkvW,
                  short* __restrict__ qkvlat)
{
  __shared__ __align__(16) short lds[65536];   // 128 KiB
  int b = blockIdx.x;
  if (b < 1024) kv256_path(xhat, Wkvf, kvbuf, kvb_i, b, (char*)lds);
  else          qkv_path(lnlat, qkvW, qkvlat, b - 1024, (char*)lds);
}

// ---------------- 128x128 GEMM (small shapes) ----------------
// EPI: 1 gelu+bf16, 4 f32 partial store (split-K z)
template<int EPI, bool HAS_BIAS>
__global__ __launch_bounds__(256, 2)
void gemm_kernel(const short* __restrict__ A, const short* __restrict__ Bt,
                 void* __restrict__ Cout, const float* __restrict__ bias,
                 int M, int N, int K, int ldk)
{
  __shared__ __align__(16) short As[128*64];
  __shared__ __align__(16) short Bs[128*64];
  const int t = threadIdx.x;
  const int lane = t & 63, w = t >> 6;
  const int m0 = blockIdx.x * 128, n0 = blockIdx.y * 128;
  const int wr = (w >> 1) * 64, wc = (w & 1) * 64;
  const short* Ap = A + (size_t)blockIdx.z * K;
  const short* Btp = Bt + (size_t)blockIdx.z * K;

  f32x4 acc[4][4];
#pragma unroll
  for (int i=0;i<4;i++)
#pragma unroll
    for (int j=0;j<4;j++) acc[i][j] = zero_f4();

  for (int kt = 0; kt < K; kt += 64) {
#pragma unroll
    for (int i = 0; i < 4; i++) {
      int chunk = i*256 + t;
      int row = chunk >> 3, slot = chunk & 7;
      int ss = slot ^ (row & 7);
      gload16(Ap + (size_t)(m0 + row)*ldk + kt + ss*8,
              (char*)As + (i*256 + (w<<6))*16);
    }
#pragma unroll
    for (int i = 0; i < 4; i++) {
      int chunk = i*256 + t;
      int row = chunk >> 3, slot = chunk & 7;
      int ss = slot ^ (row & 7);
      gload16(Btp + (size_t)(n0 + row)*ldk + kt + ss*8,
              (char*)Bs + (i*256 + (w<<6))*16);
    }
    __syncthreads();

#pragma unroll
    for (int ks = 0; ks < 2; ks++) {
      bf16x8 af[4], bfr[4];
#pragma unroll
      for (int i=0;i<4;i++) {
        int row = wr + i*16 + (lane & 15);
        int slot = (ks*4 + (lane >> 4)) ^ (row & 7);
        af[i] = *(const bf16x8*)((const char*)As + row*128 + slot*16);
        int nrow = wc + i*16 + (lane & 15);
        int nslot = (ks*4 + (lane >> 4)) ^ (nrow & 7);
        bfr[i] = *(const bf16x8*)((const char*)Bs + nrow*128 + nslot*16);
      }
#pragma unroll
      for (int i=0;i<4;i++)
#pragma unroll
        for (int j=0;j<4;j++)
          acc[i][j] = __builtin_amdgcn_mfma_f32_16x16x32_bf16(af[i], bfr[j], acc[i][j], 0, 0, 0);
    }
    __syncthreads();
  }

  const int g = lane >> 4;
#pragma unroll
  for (int i=0;i<4;i++) {
#pragma unroll
    for (int j=0;j<4;j++) {
#pragma unroll
      for (int r=0;r<4;r++) {
        int m = m0 + wr + i*16 + g*4 + r;
        int n = n0 + wc + j*16 + (lane & 15);
        float v = acc[i][j][r];
        if (EPI == 1) {
          if (HAS_BIAS) v += bias[n];
          float gl = 0.5f * v * (1.0f + erff(v * 0.70710678f));
          ((short*)Cout)[(size_t)m*N + n] = f2bf(gl);
        } else {
          ((float*)Cout)[(size_t)blockIdx.z*M*N + (size_t)m*N + n] = v;
        }
      }
    }
  }
}

// ---------------- Wo reduce (4 partials) + residual + ffln LN -> hbuf ----------------
__global__ __launch_bounds__(256)
void wored_ffln_kernel(const float* __restrict__ part, float* __restrict__ lat,
                       const float* __restrict__ w, const float* __restrict__ bb,
                       short* __restrict__ hbuf)
{
  __shared__ float sh[8];
  int r = blockIdx.x, t = threadIdx.x;
  int idx = r*256 + t;
  float4 a = ((float4*)lat)[idx];
#pragma unroll
  for (int z = 0; z < 4; z++) {
    float4 p = ((const float4*)(part + (size_t)z*LROWS*DIM))[idx];
    a.x += p.x; a.y += p.y; a.z += p.z; a.w += p.w;
  }
  ((float4*)lat)[idx] = a;
  float s = a.x+a.y+a.z+a.w;
  float sq = a.x*a.x+a.y*a.y+a.z*a.z+a.w*a.w;
  reduce2s(s, sq, sh);
  float mean = s*(1.0f/DIM), var = sq*(1.0f/DIM) - mean*mean;
  float rs = rsqrtf(var + 1e-5f);
  float4 wv = ((const float4*)w)[t], bv = ((const float4*)bb)[t];
  short4 o;
  o.x = f2bf((a.x-mean)*rs*wv.x + bv.x);
  o.y = f2bf((a.y-mean)*rs*wv.y + bv.y);
  o.z = f2bf((a.z-mean)*rs*wv.z + bv.z);
  o.w = f2bf((a.w-mean)*rs*wv.w + bv.w);
  ((short4*)(hbuf + (size_t)r*DIM))[t] = o;
}

// ---------------- W2 split-K reduce + residual + LN(next lnl or final fln) ----------------
template<bool LAST>
__global__ __launch_bounds__(256)
void w2red_ln_kernel(const float* __restrict__ part, const float* __restrict__ b2,
                     float* __restrict__ lat, const float* __restrict__ w,
                     const float* __restrict__ bb, void* __restrict__ dst)
{
  __shared__ float sh[8];
  int r = blockIdx.x, t = threadIdx.x;
  int idx = r*256 + t;
  float4 a = ((float4*)lat)[idx];
  float4 b4 = ((const float4*)b2)[t];
  a.x += b4.x; a.y += b4.y; a.z += b4.z; a.w += b4.w;
#pragma unroll
  for (int z = 0; z < 4; z++) {
    float4 p = ((const float4*)(part + (size_t)z*LROWS*DIM))[idx];
    a.x += p.x; a.y += p.y; a.z += p.z; a.w += p.w;
  }
  ((float4*)lat)[idx] = a;
  float s = a.x+a.y+a.z+a.w;
  float sq = a.x*a.x+a.y*a.y+a.z*a.z+a.w*a.w;
  reduce2s(s, sq, sh);
  float mean = s*(1.0f/DIM), var = sq*(1.0f/DIM) - mean*mean;
  float rs = rsqrtf(var + 1e-5f);
  float4 wv = ((const float4*)w)[t], bv = ((const float4*)bb)[t];
  float o0 = (a.x-mean)*rs*wv.x + bv.x;
  float o1 = (a.y-mean)*rs*wv.y + bv.y;
  float o2 = (a.z-mean)*rs*wv.z + bv.z;
  float o3 = (a.w-mean)*rs*wv.w + bv.w;
  if (LAST) {
    float4 o; o.x=o0; o.y=o1; o.z=o2; o.w=o3;
    ((float4*)((float*)dst + (size_t)r*DIM))[t] = o;
  } else {
    short4 o; o.x=f2bf(o0); o.y=f2bf(o1); o.z=f2bf(o2); o.w=f2bf(o3);
    ((short4*)((short*)dst + (size_t)r*DIM))[t] = o;
  }
}

// ---------------- attention pass 1: 4-way split-K flash, register softmax ----------------
__global__ __launch_bounds__(256, 2)
void attn_part_kernel(const short* __restrict__ qkvlat, const short* __restrict__ kvbuf,
                      float* __restrict__ part_O, float* __restrict__ part_m,
                      float* __restrict__ part_l)
{
  __shared__ __align__(16) short q_sh[64*64];
  __shared__ __align__(16) short K_sh[128*64];
  __shared__ __align__(16) short VT_sh[64*128];
  __shared__ __align__(16) short P_sh[64*132];

  const int t = threadIdx.x, lane = t & 63, w = t >> 6;
  const int bid = blockIdx.x;
  const int s = bid & 3, bh = bid >> 2;
  const int h = bh & 7, bt = bh >> 3;

  {
    const short* qsrc = qkvlat + (size_t)(bt*64)*QKVN + h*64;
#pragma unroll
    for (int i = 0; i < 2; i++) {
      int chunk = i*256 + t;
      int row = chunk >> 3, slot = chunk & 7;
      gload16(qsrc + (size_t)row*QKVN + ((slot ^ (row & 7))*8),
              (char*)q_sh + (i*256 + (w<<6))*16);
    }
  }

  float m_run[4], l_run[4];
#pragma unroll
  for (int r=0;r<4;r++){ m_run[r] = -1e30f; l_run[r] = 0.f; }
  f32x4 oacc[4];
#pragma unroll
  for (int j=0;j<4;j++) oacc[j] = zero_f4();

  const int nch = (s == 3) ? 9 : 8;
  for (int c5 = 0; c5 < nch; c5++) {
    __syncthreads();
    const bool isLat = (c5 == 8);
    const int jv = isLat ? 4 : 8;
    const short* kbase; int kstride, valid;
    if (!isLat) {
      kbase = kvbuf + ((size_t)bt*4096 + (s*8 + c5)*128)*DIM + h*64;
      kstride = DIM; valid = 128;
    } else {
      kbase = qkvlat + (size_t)(bt*64)*QKVN + 512 + h*64;
      kstride = QKVN; valid = 64;
    }
    const short* vbase = kbase + 512;

#pragma unroll
    for (int i = 0; i < 4; i++) {
      int chunk = i*256 + t;
      int row = chunk >> 3, slot = chunk & 7;
      gload16(kbase + (size_t)row*kstride + ((slot ^ (row & 7))*8),
              (char*)K_sh + (i*256 + (w<<6))*16);
    }
#pragma unroll
    for (int i = 0; i < 4; i++) {
      int c = i*256 + t;
      int row = c >> 3, slot = c & 7;
      bf16x8 v = (row < valid) ? *(const bf16x8*)(vbase + (size_t)row*kstride + slot*8) : zero_b8();
#pragma unroll
      for (int e=0;e<8;e++) {
        int dh = slot*8 + e;
        VT_sh[dh*128 + ((row + (dh & 0x78)) & 127)] = v[e];
      }
    }
    __syncthreads();

    f32x4 sacc[8];
#pragma unroll
    for (int j=0;j<8;j++) sacc[j] = zero_f4();
#pragma unroll
    for (int ks=0; ks<2; ks++) {
      int arow = w*16 + (lane & 15);
      int aslot = (ks*4 + (lane >> 4)) ^ (arow & 7);
      bf16x8 af = *(const bf16x8*)((const char*)q_sh + arow*128 + aslot*16);
#pragma unroll
      for (int j=0;j<8;j++) {
        int brow = j*16 + (lane & 15);
        int bslot = (ks*4 + (lane >> 4)) ^ (brow & 7);
        bf16x8 bv = *(const bf16x8*)((const char*)K_sh + brow*128 + bslot*16);
        sacc[j] = __builtin_amdgcn_mfma_f32_16x16x32_bf16(af, bv, sacc[j], 0, 0, 0);
      }
    }

    float mx[4];
#pragma unroll
    for (int r=0;r<4;r++) mx[r] = -1e30f;
#pragma unroll
    for (int j=0;j<8;j++) {
      if (j < jv) {
#pragma unroll
        for (int r=0;r<4;r++) mx[r] = fmaxf(mx[r], sacc[j][r]);
      }
    }
#pragma unroll
    for (int m2=1; m2<16; m2<<=1) {
#pragma unroll
      for (int r=0;r<4;r++) mx[r] = fmaxf(mx[r], __shfl_xor(mx[r], m2, 64));
    }
    float alpha[4], rowsum[4];
#pragma unroll
    for (int r=0;r<4;r++) {
      float nm = fmaxf(m_run[r], mx[r]);
      alpha[r] = __expf(m_run[r] - nm);
      m_run[r] = nm;
      rowsum[r] = 0.f;
    }
#pragma unroll
    for (int j=0;j<8;j++) {
#pragma unroll
      for (int r=0;r<4;r++) {
        float p = 0.f;
        if (j < jv) { p = __expf(sacc[j][r] - m_run[r]); rowsum[r] += p; }
        P_sh[(w*16 + (lane>>4)*4 + r)*132 + j*16 + (lane & 15)] = f2bf(p);
      }
    }
#pragma unroll
    for (int m2=1; m2<16; m2<<=1) {
#pragma unroll
      for (int r=0;r<4;r++) rowsum[r] += __shfl_xor(rowsum[r], m2, 64);
    }
#pragma unroll
    for (int r=0;r<4;r++) l_run[r] = l_run[r]*alpha[r] + rowsum[r];
#pragma unroll
    for (int j=0;j<4;j++) {
#pragma unroll
      for (int r=0;r<4;r++) oacc[j][r] *= alpha[r];
    }
    __syncthreads();

#pragma unroll
    for (int ks=0; ks<4; ks++) {
      int prow = w*16 + (lane & 15);
      bf16x8 af = *(const bf16x8*)((const char*)P_sh + prow*264 + ks*64 + (lane >> 4)*16);
#pragma unroll
      for (int j=0;j<4;j++) {
        int dh = j*16 + (lane & 15);
        int kb = (ks*4 + (lane >> 4))*8;
        const short* vp = VT_sh + dh*128 + ((kb + (dh & 0x78)) & 127);
        bf16x8 bv = *(const bf16x8*)vp;
        oacc[j] = __builtin_amdgcn_mfma_f32_16x16x32_bf16(af, bv, oacc[j], 0, 0, 0);
      }
    }
  }

  {
    float* Ob = part_O + (size_t)bid*4096;
    int rbase = w*16 + (lane>>4)*4;
#pragma unroll
    for (int j=0;j<4;j++) {
#pragma unroll
      for (int r=0;r<4;r++)
        Ob[(rbase + r)*64 + j*16 + (lane & 15)] = oacc[j][r];
    }
    if ((lane & 15) == 0) {
#pragma unroll
      for (int r=0;r<4;r++) {
        part_m[(size_t)bid*64 + rbase + r] = m_run[r];
        part_l[(size_t)bid*64 + rbase + r] = l_run[r];
      }
    }
  }
}

// ---------------- attention pass 2: combine 4 splits ----------------
__global__ __launch_bounds__(256)
void attn_combine_kernel(const float* __restrict__ part_O, const float* __restrict__ part_m,
                         const float* __restrict__ part_l, short* __restrict__ obuf)
{
  int bh = blockIdx.x, t = threadIdx.x;
  int q = t >> 2, c0 = (t & 3) * 16;
  int bt = bh >> 3, h = bh & 7;
  float m4[4], w4[4];
  float mmax = -1e30f;
#pragma unroll
  for (int s=0;s<4;s++) { m4[s] = part_m[(size_t)(bh*4+s)*64 + q]; mmax = fmaxf(mmax, m4[s]); }
  float lt = 0.f;
#pragma unroll
  for (int s=0;s<4;s++) { w4[s] = __expf(m4[s] - mmax); lt += w4[s] * part_l[(size_t)(bh*4+s)*64 + q]; }
  float inv = 1.0f / lt;
  float4 acc[4];
#pragma unroll
  for (int u=0;u<4;u++) { acc[u].x=0.f; acc[u].y=0.f; acc[u].z=0.f; acc[u].w=0.f; }
#pragma unroll
  for (int s=0;s<4;s++) {
    const float4* Ob = (const float4*)(part_O + ((size_t)(bh*4+s)*64 + q)*64 + c0);
#pragma unroll
    for (int u=0;u<4;u++) {
      float4 v = Ob[u];
      acc[u].x += w4[s]*v.x; acc[u].y += w4[s]*v.y;
      acc[u].z += w4[s]*v.z; acc[u].w += w4[s]*v.w;
    }
  }
  short* ob = obuf + (size_t)(bt*64 + q)*INNER + h*64 + c0;
#pragma unroll
  for (int u=0;u<4;u++) {
    short4 o;
    o.x = f2bf(acc[u].x*inv); o.y = f2bf(acc[u].y*inv);
    o.z = f2bf(acc[u].z*inv); o.w = f2bf(acc[u].w*inv);
    ((short4*)ob)[u] = o;
  }
}

// ---------------- launch ----------------
extern "C" void kernel_launch(void* const* d_in, const int* in_sizes, int n_in,
                              void* d_out, int out_size, void* d_ws, size_t ws_size,
                              hipStream_t stream)
{
  (void)in_sizes; (void)n_in; (void)out_size; (void)ws_size;
  const float* x        = (const float*)d_in[0];
  const float* latents  = (const float*)d_in[1];
  const float* frame_e  = (const float*)d_in[2];
  const float* media_e  = (const float*)d_in[3];
  const float* lnm_w    = (const float*)d_in[4];
  const float* lnm_b    = (const float*)d_in[5];
  const float* lnl_w    = (const float*)d_in[6];
  const float* lnl_b    = (const float*)d_in[7];
  const float* Wq       = (const float*)d_in[8];
  const float* Wkv      = (const float*)d_in[9];
  const float* Wo       = (const float*)d_in[10];
  const float* ffln_w   = (const float*)d_in[11];
  const float* ffln_b   = (const float*)d_in[12];
  const float* W1       = (const float*)d_in[13];
  const float* b1       = (const float*)d_in[14];
  const float* W2       = (const float*)d_in[15];
  const float* b2       = (const float*)d_in[16];
  const float* fln_w    = (const float*)d_in[17];
  const float* fln_b    = (const float*)d_in[18];
  float* out = (float*)d_out;

  char* ws = (char*)d_ws;
  size_t off = 0;
  short* xhat   = (short*)(ws + off); off += (size_t)XROWS*DIM*2;
  short* kvbuf  = (short*)(ws + off); off += (size_t)XROWS*DIM*2;
  short* Wkvf_a = (short*)(ws + off); off += (size_t)DEPTH*DIM*DIM*2;
  short* qkvW_a = (short*)(ws + off); off += (size_t)DEPTH*QKVN*DIM*2;
  short* Wo_a   = (short*)(ws + off); off += (size_t)DEPTH*INNER*DIM*2;
  short* W1_a   = (short*)(ws + off); off += (size_t)DEPTH*DIM*FFD*2;
  short* W2_a   = (short*)(ws + off); off += (size_t)DEPTH*FFD*DIM*2;
  float* kvb    = (float*)(ws + off); off += (size_t)DEPTH*DIM*4;
  float* kvbp   = (float*)(ws + off); off += (size_t)DEPTH*16*DIM*4;
  float* lat    = (float*)(ws + off); off += (size_t)LROWS*DIM*4;
  short* lnlat  = (short*)(ws + off); off += (size_t)LROWS*DIM*2;
  short* qkvlat = (short*)(ws + off); off += (size_t)LROWS*QKVN*2;
  short* obuf   = (short*)(ws + off); off += (size_t)LROWS*INNER*2;
  short* hbuf   = (short*)(ws + off); off += (size_t)LROWS*DIM*2;
  short* h1     = (short*)(ws + off); off += (size_t)LROWS*FFD*2;
  float* wopart = (float*)(ws + off); off += (size_t)4*LROWS*DIM*4;
  // part_O (attn, 8MB) and w2part (ffn, 16MB) live at disjoint times: share (16MB)
  float* part_O = (float*)(ws + off); off += (size_t)4*LROWS*DIM*4;
  float* w2part = part_O;
  float* part_m = (float*)(ws + off); off += (size_t)512*64*4;
  float* part_l = (float*)(ws + off); off += (size_t)512*64*4;

  mega0_kernel<<<34400, 256, 0, stream>>>(
      x, frame_e, media_e, xhat,
      latents, lnl_w, lnl_b, lat, lnlat,
      Wkv, Wq, Wo, W1, W2, lnm_w,
      Wkvf_a, qkvW_a, Wo_a, W1_a, W2_a,
      lnm_b, kvbp);
  kvbred_kernel<<<DEPTH, 256, 0, stream>>>(kvbp, kvb);

  for (int i = 0; i < DEPTH; i++) {
    const short* Wkv_f = Wkvf_a + (size_t)i*DIM*DIM;
    const short* qkvW  = qkvW_a + (size_t)i*QKVN*DIM;
    const short* Wo_h  = Wo_a   + (size_t)i*INNER*DIM;
    const short* W1_h  = W1_a   + (size_t)i*DIM*FFD;
    const short* W2_h  = W2_a   + (size_t)i*FFD*DIM;

    mega1_kernel<<<1120, 512, 0, stream>>>(
        xhat, Wkv_f, kvb + i*DIM, kvbuf, lnlat, qkvW, qkvlat);
    attn_part_kernel<<<512, 256, 0, stream>>>(qkvlat, kvbuf, part_O, part_m, part_l);
    attn_combine_kernel<<<128, 256, 0, stream>>>(part_O, part_m, part_l, obuf);
    gemm_kernel<4,false><<<dim3(LROWS/128, DIM/128, 4), 256, 0, stream>>>(
        obuf, Wo_h, wopart, nullptr, LROWS, DIM, 128, INNER);
    wored_ffln_kernel<<<LROWS, 256, 0, stream>>>(
        wopart, lat, ffln_w + i*DIM, ffln_b + i*DIM, hbuf);
    gemm_kernel<1,true><<<dim3(LROWS/128, FFD/128), 256, 0, stream>>>(
        hbuf, W1_h, h1, b1 + (size_t)i*FFD, LROWS, FFD, DIM, DIM);
    gemm_kernel<4,false><<<dim3(LROWS/128, DIM/128, 4), 256, 0, stream>>>(
        h1, W2_h, w2part, nullptr, LROWS, DIM, DIM, FFD);
    if (i < DEPTH-1)
      w2red_ln_kernel<false><<<LROWS, 256, 0, stream>>>(
          w2part, b2 + (size_t)i*DIM, lat, lnl_w + (i+1)*DIM, lnl_b + (i+1)*DIM, lnlat);
    else
      w2red_ln_kernel<true><<<LROWS, 256, 0, stream>>>(
          w2part, b2 + (size_t)i*DIM, lat, fln_w, fln_b, out);
  }
}